// Round 9
// baseline (222.507 us; speedup 1.0000x reference)
//
#include <hip/hip_runtime.h>
#include <cstdint>
#include <cstddef>
#include <type_traits>

// ---------------------------------------------------------------------------
// FlashSparseAttention: X->QKV proj -> RoPE -> causal GQA flash attn -> O proj
// B=2 S=2048 H=2048 NH=16 NKV=4 HD=128, fp32 in/out, bf16 MFMA internally.
// R9: GEMMs re-tiled 128x128/BK=32, 4 waves, 48KB 3-slot ring -> 3 blocks/CU
//     (QKV grid 768 = 3/CU exact, O-proj 512 = 2/CU). Cross-block overlap
//     replaces the dead 1-block/CU barrier coupling of R8's 256-wide tiles.
//     Attention kernel unchanged from R8 (32x32 swapped-QK^T structure).
// ---------------------------------------------------------------------------

typedef __bf16 bf16x8 __attribute__((ext_vector_type(8)));
typedef float f32x4 __attribute__((ext_vector_type(4)));
typedef float f32x16 __attribute__((ext_vector_type(16)));
typedef int i32x4 __attribute__((ext_vector_type(4)));

#define DEVFN static __device__ __forceinline__

constexpr int Bc = 2, Sc = 2048, Hc = 2048, NHc = 16, NKVc = 4, HDc = 128;
constexpr float SM_SCALE = 0.08838834764831845f;   // 1/sqrt(128)
constexpr float QSCALE = 0.127517431f;             // SM_SCALE * log2(e)
constexpr float DEFER_THR = 11.0f;                 // ~8 nats in log2 domain

DEVFN unsigned short f2bf(float f) {
  __bf16 h = (__bf16)f;
  return __builtin_bit_cast(unsigned short, h);
}
DEVFN float bf2f(unsigned short s) { return __uint_as_float(((unsigned)s) << 16); }

DEVFN unsigned cvtpk(float lo, float hi) {
  unsigned r;
  asm("v_cvt_pk_bf16_f32 %0, %1, %2" : "=v"(r) : "v"(lo), "v"(hi));
  return r;
}
DEVFN void pswap(unsigned& x, unsigned& y) {
  asm("v_permlane32_swap_b32 %0, %1" : "+v"(x), "+v"(y));
}

DEVFN f32x16 mfma32(bf16x8 a, bf16x8 b, f32x16 c) {
  return __builtin_amdgcn_mfma_f32_32x32x16_bf16(a, b, c, 0, 0, 0);
}

DEVFN void gload_lds16(const void* g, void* l) {
  __builtin_amdgcn_global_load_lds(
      (const __attribute__((address_space(1))) unsigned int*)g,
      (__attribute__((address_space(3))) unsigned int*)l, 16, 0, 0);
}

// ---------------- fp32 -> bf16 conversion (vectorized x4) ------------------
__global__ __launch_bounds__(256) void cvt_kernel(const float* __restrict__ in,
                                                  unsigned short* __restrict__ out,
                                                  int n4) {
  int i = blockIdx.x * 256 + threadIdx.x;
  if (i >= n4) return;
  float4 v = reinterpret_cast<const float4*>(in)[i];
  ushort4 o;
  o.x = f2bf(v.x); o.y = f2bf(v.y); o.z = f2bf(v.z); o.w = f2bf(v.w);
  reinterpret_cast<ushort4*>(out)[i] = o;
}

// ---------------- fused weight conversion (Wq|Wk|Wv -> Wqkv, Wo -> Wob) ----
__global__ __launch_bounds__(256) void cvt_weights(const float* __restrict__ Wq,
                                                   const float* __restrict__ Wk,
                                                   const float* __restrict__ Wv,
                                                   const float* __restrict__ Wo,
                                                   unsigned short* __restrict__ Wqkv,
                                                   unsigned short* __restrict__ Wob) {
  const int i = blockIdx.x * 256 + threadIdx.x;  // float4 index, total 2621440
  const float* src;
  unsigned short* dst;
  int off;
  if (i < 1048576) { src = Wq; dst = Wqkv; off = i; }
  else if (i < 1310720) { src = Wk; dst = Wqkv + 4194304; off = i - 1048576; }
  else if (i < 1572864) { src = Wv; dst = Wqkv + 5242880; off = i - 1310720; }
  else { src = Wo; dst = Wob; off = i - 1572864; }
  float4 v = reinterpret_cast<const float4*>(src)[off];
  ushort4 o;
  o.x = f2bf(v.x); o.y = f2bf(v.y); o.z = f2bf(v.z); o.w = f2bf(v.w);
  reinterpret_cast<ushort4*>(dst)[off] = o;
}

// ---------------- RoPE cos/sin table: [s][d] d in 0..63, f32 ---------------
__global__ __launch_bounds__(256) void rope_table(float* __restrict__ cosT,
                                                  float* __restrict__ sinT) {
  const int i = blockIdx.x * 256 + threadIdx.x;  // 131072 = 2048*64
  const int s = i >> 6, d = i & 63;
  const float inv = exp2f(-0.2076205059304601f * (float)d);  // 10000^(-d/64)
  float sn, c;
  sincosf((float)s * inv, &sn, &c);
  cosT[i] = c;
  sinT[i] = sn;
}

// ---------------- ring-pipelined NT GEMM, 128x128 tile, BK=32 ---------------
// 4 waves (2x2, 64x64 each), 3-slot LDS ring (48KB -> 3 blocks/CU), counted
// vmcnt(4), 1 barrier per K-tile, conflict-free swizzle chunk^=(row>>1)&3
// (2-way aliasing only), XCD block swizzle. M = 4096, K = 2048 fixed.
// MODE 1: f32 out N=2048; MODE 2: fused QKV epilogue (Q bf16 / K bf16 / V^T).
template <int NBN, int MODE>
__global__ __launch_bounds__(256, 3) void gemm_ring(const unsigned short* __restrict__ A,
                                                    const unsigned short* __restrict__ Bw,
                                                    void* __restrict__ o0,
                                                    void* __restrict__ o1,
                                                    void* __restrict__ o2) {
  constexpr int T = 64;                    // K-tiles (K/32)
  __shared__ __align__(16) char smem[49152];

  const int tid = threadIdx.x;
  const int w = tid >> 6, l = tid & 63;
  const int g = l >> 4, lc = l & 15;
  const int wm = (w >> 1) << 6, wn = (w & 1) << 6;

  const int bid = blockIdx.x;              // grid = NBN*32, multiple of 8
  const int wgid = (bid & 7) * (NBN * 4) + (bid >> 3);
  const int bm = (wgid & 31) << 7;
  const int bn = (wgid >> 5) << 7;

  // ---- staging lane constants (pre-swizzled global source; linear LDS) ----
  const int srow = tid >> 2;                                   // 0..63
  const int scb = (((tid & 3) ^ ((tid >> 3) & 3)) << 4);       // swizzled 16B chunk
  const char* Agp = (const char*)A + ((size_t)(bm + srow) << 12) + scb;
  const char* Bgp = (const char*)Bw + ((size_t)(bn + srow) << 12) + scb;
  char* ldst = smem + tid * 16;

  auto stage = [&](int slot, int kt) {
    const int kb = kt << 6;                                    // K byte offset
    gload_lds16(Agp + kb, ldst + slot);                        // A rows 0-63
    gload_lds16(Agp + (64ull << 12) + kb, ldst + slot + 4096); // A rows 64-127
    gload_lds16(Bgp + kb, ldst + slot + 8192);                 // B rows 0-63
    gload_lds16(Bgp + (64ull << 12) + kb, ldst + slot + 12288);// B rows 64-127
  };

  // ---- read lane constants: frag row = base+lc, 16B chunk g (swizzled) ----
  const int rowA = wm + lc;
  const int laneA = rowA * 64 + ((g ^ ((rowA >> 1) & 3)) << 4);
  const int rowB = wn + lc;
  const int laneB = 8192 + rowB * 64 + ((g ^ ((rowB >> 1) & 3)) << 4);

  f32x4 zero4 = {0.f, 0.f, 0.f, 0.f};
  f32x4 acc[4][4];
#pragma unroll
  for (int i = 0; i < 4; i++)
#pragma unroll
    for (int j = 0; j < 4; j++) acc[i][j] = zero4;

  stage(0, 0);
  stage(16384, 1);

  auto ktile = [&](int j, auto slotc) {
    constexpr int SB = decltype(slotc)::value;
    constexpr int SB2 = (SB + 32768) % 49152;
    if (j < T - 1) {
      asm volatile("s_waitcnt vmcnt(4)" ::: "memory");
    } else {
      asm volatile("s_waitcnt vmcnt(0)" ::: "memory");
    }
    asm volatile("s_barrier" ::: "memory");
    if (j + 2 < T) stage(SB2, j + 2);

    bf16x8 af[4], bfr[4];
#pragma unroll
    for (int mi = 0; mi < 4; mi++) af[mi] = *(const bf16x8*)(smem + SB + laneA + mi * 1024);
#pragma unroll
    for (int nj = 0; nj < 4; nj++) bfr[nj] = *(const bf16x8*)(smem + SB + laneB + nj * 1024);

    __builtin_amdgcn_s_setprio(1);
#pragma unroll
    for (int mi = 0; mi < 4; mi++)
#pragma unroll
      for (int nj = 0; nj < 4; nj++)
        acc[mi][nj] = __builtin_amdgcn_mfma_f32_16x16x32_bf16(af[mi], bfr[nj], acc[mi][nj], 0, 0, 0);
    __builtin_amdgcn_s_setprio(0);
  };

  for (int t3 = 0; t3 < 21; ++t3) {        // 64 = 3*21 + 1
    ktile(3 * t3, std::integral_constant<int, 0>{});
    ktile(3 * t3 + 1, std::integral_constant<int, 16384>{});
    ktile(3 * t3 + 2, std::integral_constant<int, 32768>{});
  }
  ktile(63, std::integral_constant<int, 0>{});

  // ---- epilogue ----
#pragma unroll
  for (int mi = 0; mi < 4; mi++) {
#pragma unroll
    for (int nj = 0; nj < 4; nj++) {
#pragma unroll
      for (int r = 0; r < 4; r++) {
        const int row = bm + wm + mi * 16 + (g << 2) + r;
        const int col = bn + wn + nj * 16 + lc;
        const float v = acc[mi][nj][r];
        if (MODE == 1) {
          ((float*)o0)[(size_t)row * 2048 + col] = v;
        } else {
          const unsigned short q = f2bf(v);
          if (bn < 2048) {
            ((unsigned short*)o0)[(size_t)row * 2048 + col] = q;
          } else if (bn < 2560) {
            ((unsigned short*)o1)[(size_t)row * 512 + (col - 2048)] = q;
          } else {
            const int cv = col - 2560;
            ((unsigned short*)o2)[((size_t)(((row >> 11) * NKVc + (cv >> 7)) * HDc + (cv & 127)) << 11) +
                                  (row & 2047)] = q;
          }
        }
      }
    }
  }
}

// ---------------- K RoPE + relayout: raw[tok][kv*128+d] -> [b][kv][s][d] ----
__global__ __launch_bounds__(256) void rope_k(const unsigned short* __restrict__ raw,
                                              unsigned short* __restrict__ dst,
                                              const float* __restrict__ cosT,
                                              const float* __restrict__ sinT) {
  const int t = blockIdx.x * 256 + threadIdx.x;
  const int d = t & 63;
  const int h = (t >> 6) & 3;
  const int tok = t >> 8;
  const int b = tok >> 11, s = tok & 2047;
  const float c = cosT[(s << 6) + d];
  const float sn = sinT[(s << 6) + d];
  const size_t src = (size_t)tok * 512 + h * 128 + d;
  const float x0 = bf2f(raw[src]);
  const float x1 = bf2f(raw[src + 64]);
  const size_t db = ((size_t)(b * NKVc + h) * Sc + s) * HDc + d;
  dst[db] = f2bf(x0 * c - x1 * sn);
  dst[db + 64] = f2bf(x1 * c + x0 * sn);
}

// ---------------- causal GQA flash attention (R8 structure, unchanged) ------
__global__ __launch_bounds__(256, 2) void attn_kernel(const unsigned short* __restrict__ Qraw,
                                                      const unsigned short* __restrict__ Kr,
                                                      const unsigned short* __restrict__ Vt,
                                                      unsigned short* __restrict__ O,
                                                      const float* __restrict__ cosT,
                                                      const float* __restrict__ sinT) {
  __shared__ __align__(16) char smem[65536];

  const int tid = threadIdx.x, w = tid >> 6, l = tid & 63;
  const int lq = l & 31, lh = l >> 5;
  const int kvb = blockIdx.x & 7, p = blockIdx.x >> 3;
  const int b = kvb >> 2, kvh = kvb & 3, h = kvh * 4 + w;
  const int t0 = 63 - p, t1 = p;
  const int NIT0 = (t0 >> 1) + 1;
  const int NIT1 = (t1 >> 1) + 1;   // NIT0 + NIT1 == 33 always

  const char* Kb = (const char*)(Kr + (size_t)(b * NKVc + kvh) * Sc * HDc);
  const char* Vb = (const char*)(Vt + (size_t)(b * NKVc + kvh) * HDc * Sc);

  const int krow0 = tid >> 4;
  const int kcb = ((tid & 15) * 16) ^ ((krow0 & 7) << 4);
  const int vrow0 = tid >> 3;
  const int vcb = ((tid & 7) * 16) ^ ((vrow0 & 7) << 4);
  char* ldst = smem + tid * 16;

  auto stage = [&](int slot, int kt_) {
#pragma unroll
    for (int c = 0; c < 4; c++)
      gload_lds16(Kb + (size_t)(kt_ * 64 + krow0 + 16 * c) * 256 + kcb,
                  ldst + slot + c * 4096);
#pragma unroll
    for (int c = 0; c < 4; c++)
      gload_lds16(Vb + (size_t)(vrow0 + 32 * c) * 4096 + kt_ * 128 + vcb,
                  ldst + slot + 16384 + c * 4096);
  };

  const int swz = (l & 7) << 4;
  const int hi16 = lh << 4;
  int co[8];
#pragma unroll
  for (int kc = 0; kc < 8; kc++) co[kc] = (kc * 32 + hi16) ^ swz;
  const int kbase = lq * 256;
  const int vbase = 16384 + lq * 128;

  bf16x8 qf[8];
  auto loadQ = [&](int t) {
    const int srow = t * 32 + lq;
    const unsigned short* Qp = Qraw + ((size_t)(b * Sc + srow) << 11) + h * 128 + lh * 8;
#pragma unroll
    for (int kc = 0; kc < 4; kc++) {
      const bf16x8 vlo = *(const bf16x8*)(Qp + kc * 16);
      const bf16x8 vhi = *(const bf16x8*)(Qp + kc * 16 + 64);
      const float* cp = cosT + ((size_t)srow << 6) + kc * 16 + lh * 8;
      const float* sp = sinT + ((size_t)srow << 6) + kc * 16 + lh * 8;
      const float4 c0 = *(const float4*)cp, c1 = *(const float4*)(cp + 4);
      const float4 s0v = *(const float4*)sp, s1v = *(const float4*)(sp + 4);
      const float cs[8] = {c0.x, c0.y, c0.z, c0.w, c1.x, c1.y, c1.z, c1.w};
      const float ss[8] = {s0v.x, s0v.y, s0v.z, s0v.w, s1v.x, s1v.y, s1v.z, s1v.w};
#pragma unroll
      for (int j = 0; j < 8; j++) {
        const float xl = (float)vlo[j] * QSCALE;
        const float xh = (float)vhi[j] * QSCALE;
        qf[kc][j] = (__bf16)(xl * cs[j] - xh * ss[j]);
        qf[kc + 4][j] = (__bf16)(xh * cs[j] + xl * ss[j]);
      }
    }
  };

  f32x16 oacc[4];
#pragma unroll
  for (int d = 0; d < 4; d++)
#pragma unroll
    for (int r = 0; r < 16; r++) oacc[d][r] = 0.f;
  float m_run = -1e30f, sum_run = 0.f;

  int kt = 0, tcur = t0, nlast = NIT0 - 1, phase = 0;
  loadQ(t0);
  stage(0, 0);

  auto iter = [&](int i, auto slotc) {
    constexpr int SLOT = decltype(slotc)::value;
    if (i < 32) {
      const int ni = i + 1;
      stage(SLOT ^ 32768, ni < NIT0 ? ni : ni - NIT0);
      asm volatile("s_waitcnt vmcnt(8)" ::: "memory");
    } else {
      asm volatile("s_waitcnt vmcnt(0)" ::: "memory");
    }
    __builtin_amdgcn_s_barrier();

    f32x16 s0, s1;
#pragma unroll
    for (int r = 0; r < 16; r++) { s0[r] = 0.f; s1[r] = 0.f; }
    __builtin_amdgcn_s_setprio(1);
#pragma unroll
    for (int kc = 0; kc < 8; kc++) {
      const bf16x8 kf0 = *(const bf16x8*)(smem + SLOT + kbase + co[kc]);
      const bf16x8 kf1 = *(const bf16x8*)(smem + SLOT + 8192 + kbase + co[kc]);
      s0 = mfma32(kf0, qf[kc], s0);
      s1 = mfma32(kf1, qf[kc], s1);
    }
    __builtin_amdgcn_s_setprio(0);

    if (kt == nlast) {
      const int qpos = tcur * 32 + lq;
      const int kv0 = kt * 64 + 4 * lh;
#pragma unroll
      for (int r = 0; r < 16; r++) {
        const int kvv = kv0 + (r & 3) + 8 * (r >> 2);
        if (kvv > qpos) s0[r] = -1e30f;
        if (kvv + 32 > qpos) s1[r] = -1e30f;
      }
    }

    float q8[8];
#pragma unroll
    for (int g4 = 0; g4 < 4; g4++) {
      q8[g4] = fmaxf(fmaxf(s0[4 * g4], s0[4 * g4 + 1]), fmaxf(s0[4 * g4 + 2], s0[4 * g4 + 3]));
      q8[4 + g4] = fmaxf(fmaxf(s1[4 * g4], s1[4 * g4 + 1]), fmaxf(s1[4 * g4 + 2], s1[4 * g4 + 3]));
    }
    float mt = fmaxf(fmaxf(fmaxf(q8[0], q8[1]), fmaxf(q8[2], q8[3])),
                     fmaxf(fmaxf(q8[4], q8[5]), fmaxf(q8[6], q8[7])));
    mt = fmaxf(mt, __shfl_xor(mt, 32));
    if (!__all(mt <= m_run + DEFER_THR)) {
      const float mn = fmaxf(m_run, mt);
      const float al = exp2f(m_run - mn);
      m_run = mn;
      sum_run *= al;
#pragma unroll
      for (int d = 0; d < 4; d++)
#pragma unroll
        for (int r = 0; r < 16; r++) oacc[d][r] *= al;
    }

    float pv0[16], pv1[16];
    float sA = 0.f, sB = 0.f, sC = 0.f, sD = 0.f;
#pragma unroll
    for (int r = 0; r < 16; r += 4) {
      pv0[r] = exp2f(s0[r] - m_run);         sA += pv0[r];
      pv0[r + 1] = exp2f(s0[r + 1] - m_run); sB += pv0[r + 1];
      pv0[r + 2] = exp2f(s0[r + 2] - m_run); sC += pv0[r + 2];
      pv0[r + 3] = exp2f(s0[r + 3] - m_run); sD += pv0[r + 3];
    }
#pragma unroll
    for (int r = 0; r < 16; r += 4) {
      pv1[r] = exp2f(s1[r] - m_run);         sA += pv1[r];
      pv1[r + 1] = exp2f(s1[r + 1] - m_run); sB += pv1[r + 1];
      pv1[r + 2] = exp2f(s1[r + 2] - m_run); sC += pv1[r + 2];
      pv1[r + 3] = exp2f(s1[r + 3] - m_run); sD += pv1[r + 3];
    }
    sum_run += (sA + sB) + (sC + sD);

    bf16x8 pf0, pf1, pf2, pf3;
    {
      unsigned a0 = cvtpk(pv0[0], pv0[1]), a2 = cvtpk(pv0[4], pv0[5]);
      unsigned a1 = cvtpk(pv0[2], pv0[3]), a3 = cvtpk(pv0[6], pv0[7]);
      pswap(a0, a2); pswap(a1, a3);
      i32x4 t4 = {(int)a0, (int)a1, (int)a2, (int)a3};
      pf0 = __builtin_bit_cast(bf16x8, t4);
    }
    {
      unsigned a0 = cvtpk(pv0[8], pv0[9]), a2 = cvtpk(pv0[12], pv0[13]);
      unsigned a1 = cvtpk(pv0[10], pv0[11]), a3 = cvtpk(pv0[14], pv0[15]);
      pswap(a0, a2); pswap(a1, a3);
      i32x4 t4 = {(int)a0, (int)a1, (int)a2, (int)a3};
      pf1 = __builtin_bit_cast(bf16x8, t4);
    }
    {
      unsigned a0 = cvtpk(pv1[0], pv1[1]), a2 = cvtpk(pv1[4], pv1[5]);
      unsigned a1 = cvtpk(pv1[2], pv1[3]), a3 = cvtpk(pv1[6], pv1[7]);
      pswap(a0, a2); pswap(a1, a3);
      i32x4 t4 = {(int)a0, (int)a1, (int)a2, (int)a3};
      pf2 = __builtin_bit_cast(bf16x8, t4);
    }
    {
      unsigned a0 = cvtpk(pv1[8], pv1[9]), a2 = cvtpk(pv1[12], pv1[13]);
      unsigned a1 = cvtpk(pv1[10], pv1[11]), a3 = cvtpk(pv1[14], pv1[15]);
      pswap(a0, a2); pswap(a1, a3);
      i32x4 t4 = {(int)a0, (int)a1, (int)a2, (int)a3};
      pf3 = __builtin_bit_cast(bf16x8, t4);
    }

    __builtin_amdgcn_s_setprio(1);
#pragma unroll
    for (int d = 0; d < 4; d++) {
      oacc[d] = mfma32(*(const bf16x8*)(smem + SLOT + vbase + d * 4096 + co[0]), pf0, oacc[d]);
      oacc[d] = mfma32(*(const bf16x8*)(smem + SLOT + vbase + d * 4096 + co[1]), pf1, oacc[d]);
      oacc[d] = mfma32(*(const bf16x8*)(smem + SLOT + vbase + d * 4096 + co[2]), pf2, oacc[d]);
      oacc[d] = mfma32(*(const bf16x8*)(smem + SLOT + vbase + d * 4096 + co[3]), pf3, oacc[d]);
    }
    __builtin_amdgcn_s_setprio(0);

    asm volatile("s_waitcnt lgkmcnt(0)" ::: "memory");

    if (kt == nlast) {
      const float st = sum_run + __shfl_xor(sum_run, 32);
      const float rinv = 1.0f / st;
      unsigned short* Op = O + ((size_t)(b * Sc + tcur * 32 + lq) << 11) + h * 128 + lh * 4;
#pragma unroll
      for (int d = 0; d < 4; d++) {
#pragma unroll
        for (int rq = 0; rq < 4; rq++) {
          uint2 u2;
          u2.x = cvtpk(oacc[d][4 * rq] * rinv, oacc[d][4 * rq + 1] * rinv);
          u2.y = cvtpk(oacc[d][4 * rq + 2] * rinv, oacc[d][4 * rq + 3] * rinv);
          *(uint2*)(Op + d * 32 + rq * 8) = u2;
        }
      }
      if (phase == 0) {
        phase = 1; tcur = t1; kt = 0; nlast = NIT1 - 1;
#pragma unroll
        for (int d = 0; d < 4; d++)
#pragma unroll
          for (int r = 0; r < 16; r++) oacc[d][r] = 0.f;
        m_run = -1e30f;
        sum_run = 0.f;
        loadQ(t1);
      }
    } else {
      kt++;
    }
  };

  for (int u2i = 0; u2i < 16; ++u2i) {
    iter(2 * u2i, std::integral_constant<int, 0>{});
    iter(2 * u2i + 1, std::integral_constant<int, 32768>{});
  }
  iter(32, std::integral_constant<int, 0>{});
}

// ---------------------------------------------------------------------------
extern "C" void kernel_launch(void* const* d_in, const int* in_sizes, int n_in,
                              void* d_out, int out_size, void* d_ws, size_t ws_size,
                              hipStream_t stream) {
  (void)in_sizes; (void)n_in; (void)out_size; (void)ws_size;
  const float* X = (const float*)d_in[0];
  const float* Wq = (const float*)d_in[1];
  const float* Wk = (const float*)d_in[2];
  const float* Wv = (const float*)d_in[3];
  const float* Wo = (const float*)d_in[4];

  char* ws = (char*)d_ws;
  unsigned short* Xbf  = (unsigned short*)(ws + 0);         // 4096x2048 (16MB)
  unsigned short* Wqkv = (unsigned short*)(ws + 16777216);  // 3072x2048 (12.6MB)
  unsigned short* Wob  = (unsigned short*)(ws + 29360128);  // 2048x2048 (8MB)
  unsigned short* Qraw = (unsigned short*)(ws + 37748736);  // 4096x2048 (16MB)
  unsigned short* Kraw = (unsigned short*)(ws + 54525952);  // 4096x512  (4MB)
  unsigned short* Vt   = (unsigned short*)(ws + 58720256);  // [b][kv][d][s] (4MB)
  float*          cosT = (float*)(ws + 62914560);           // 2048x64 f32 (512KB)
  float*          sinT = (float*)(ws + 63438848);           // 2048x64 f32 (512KB)
  unsigned short* Kr   = (unsigned short*)(ws + 79691776);  // [b][kv][s][d] (4MB)
  unsigned short* Ows  = (unsigned short*)(ws + 83886080);  // 4096x2048 (16MB)

  rope_table<<<512, 256, 0, stream>>>(cosT, sinT);
  cvt_kernel<<<8192, 256, 0, stream>>>(X, Xbf, 2097152);
  cvt_weights<<<10240, 256, 0, stream>>>(Wq, Wk, Wv, Wo, Wqkv, Wob);

  gemm_ring<24, 2><<<768, 256, 0, stream>>>(Xbf, Wqkv, Qraw, Kraw, Vt);

  rope_k<<<4096, 256, 0, stream>>>(Kraw, Kr, cosT, sinT);

  attn_kernel<<<256, 256, 0, stream>>>(Qraw, Kr, Vt, Ows, cosT, sinT);

  gemm_ring<16, 1><<<512, 256, 0, stream>>>(Ows, Wob, d_out, nullptr, nullptr);
}

// Round 10
// 218.750 us; speedup vs baseline: 1.0172x; 1.0172x over previous
//
#include <hip/hip_runtime.h>
#include <cstdint>
#include <cstddef>
#include <type_traits>

// ---------------------------------------------------------------------------
// FlashSparseAttention: X->QKV proj -> RoPE -> causal GQA flash attn -> O proj
// B=2 S=2048 H=2048 NH=16 NKV=4 HD=128, fp32 in/out, bf16 MFMA internally.
// R10: GEMMs rewritten to the 256-wide 8-phase template (T2+T3+T4+T5):
//      BK=64, 8 waves, 2-buffer LDS, per-phase {ds_read || 1 half-tile
//      global_load_lds -> barrier -> 16 MFMA -> barrier}, counted vmcnt(8/6)
//      only at K-half boundaries (never 0 mid-loop). Half-tiles are K-halves
//      so slots are reused immediately after consumption (audited schedule).
//      QKV: 256x256 grid 192; O-proj: 256x128 grid 256 (full chip).
//      Attention unchanged from R8/R9.
// ---------------------------------------------------------------------------

typedef __bf16 bf16x8 __attribute__((ext_vector_type(8)));
typedef float f32x4 __attribute__((ext_vector_type(4)));
typedef float f32x16 __attribute__((ext_vector_type(16)));
typedef int i32x4 __attribute__((ext_vector_type(4)));

#define DEVFN static __device__ __forceinline__

constexpr int Bc = 2, Sc = 2048, Hc = 2048, NHc = 16, NKVc = 4, HDc = 128;
constexpr float SM_SCALE = 0.08838834764831845f;   // 1/sqrt(128)
constexpr float QSCALE = 0.127517431f;             // SM_SCALE * log2(e)
constexpr float DEFER_THR = 11.0f;                 // ~8 nats in log2 domain

DEVFN unsigned short f2bf(float f) {
  __bf16 h = (__bf16)f;
  return __builtin_bit_cast(unsigned short, h);
}
DEVFN float bf2f(unsigned short s) { return __uint_as_float(((unsigned)s) << 16); }

DEVFN unsigned cvtpk(float lo, float hi) {
  unsigned r;
  asm("v_cvt_pk_bf16_f32 %0, %1, %2" : "=v"(r) : "v"(lo), "v"(hi));
  return r;
}
DEVFN void pswap(unsigned& x, unsigned& y) {
  asm("v_permlane32_swap_b32 %0, %1" : "+v"(x), "+v"(y));
}

DEVFN f32x16 mfma32(bf16x8 a, bf16x8 b, f32x16 c) {
  return __builtin_amdgcn_mfma_f32_32x32x16_bf16(a, b, c, 0, 0, 0);
}
DEVFN f32x4 mfma16(bf16x8 a, bf16x8 b, f32x4 c) {
  return __builtin_amdgcn_mfma_f32_16x16x32_bf16(a, b, c, 0, 0, 0);
}

DEVFN void gload_lds16(const void* g, void* l) {
  __builtin_amdgcn_global_load_lds(
      (const __attribute__((address_space(1))) unsigned int*)g,
      (__attribute__((address_space(3))) unsigned int*)l, 16, 0, 0);
}

#define BAR() __builtin_amdgcn_s_barrier()

// ---------------- fp32 -> bf16 conversion (vectorized x4) ------------------
__global__ __launch_bounds__(256) void cvt_kernel(const float* __restrict__ in,
                                                  unsigned short* __restrict__ out,
                                                  int n4) {
  int i = blockIdx.x * 256 + threadIdx.x;
  if (i >= n4) return;
  float4 v = reinterpret_cast<const float4*>(in)[i];
  ushort4 o;
  o.x = f2bf(v.x); o.y = f2bf(v.y); o.z = f2bf(v.z); o.w = f2bf(v.w);
  reinterpret_cast<ushort4*>(out)[i] = o;
}

// ---------------- fused weight conversion (Wq|Wk|Wv -> Wqkv, Wo -> Wob) ----
__global__ __launch_bounds__(256) void cvt_weights(const float* __restrict__ Wq,
                                                   const float* __restrict__ Wk,
                                                   const float* __restrict__ Wv,
                                                   const float* __restrict__ Wo,
                                                   unsigned short* __restrict__ Wqkv,
                                                   unsigned short* __restrict__ Wob) {
  const int i = blockIdx.x * 256 + threadIdx.x;  // float4 index, total 2621440
  const float* src;
  unsigned short* dst;
  int off;
  if (i < 1048576) { src = Wq; dst = Wqkv; off = i; }
  else if (i < 1310720) { src = Wk; dst = Wqkv + 4194304; off = i - 1048576; }
  else if (i < 1572864) { src = Wv; dst = Wqkv + 5242880; off = i - 1310720; }
  else { src = Wo; dst = Wob; off = i - 1572864; }
  float4 v = reinterpret_cast<const float4*>(src)[off];
  ushort4 o;
  o.x = f2bf(v.x); o.y = f2bf(v.y); o.z = f2bf(v.z); o.w = f2bf(v.w);
  reinterpret_cast<ushort4*>(dst)[off] = o;
}

// ---------------- RoPE cos/sin table: [s][d] d in 0..63, f32 ---------------
__global__ __launch_bounds__(256) void rope_table(float* __restrict__ cosT,
                                                  float* __restrict__ sinT) {
  const int i = blockIdx.x * 256 + threadIdx.x;  // 131072 = 2048*64
  const int s = i >> 6, d = i & 63;
  const float inv = exp2f(-0.2076205059304601f * (float)d);  // 10000^(-d/64)
  float sn, c;
  sincosf((float)s * inv, &sn, &c);
  cosT[i] = c;
  sinT[i] = sn;
}

// ---------------- 8-phase deep-pipelined NT GEMM (BM=256, BK=64) ------------
// 8 waves (2M x 4N, 512 thr). LDS: 2 buffers, each = A[2 kk][256][32k] +
// B[2 kk][BN][32k] bf16 (64B rows, swizzle g16 ^= (row>>1)&3, both-sides).
// Per K-tile: BN=256 -> 4 phases (kk x N-half), BN=128 -> 2 phases (kk).
// Each phase: ds_read frags || stage 1 half-tile (K-half of A or B) of a
// future K-tile into a just-consumed slot -> barrier -> 16 MFMA -> barrier.
// Counted vmcnt(8)/(6) at K-half boundaries only; audited prologue/tail.
// MODE 2: fused QKV epilogue (N=3072, grid 192); MODE 1: f32 out (grid 256).
template <int BN, int MODE>
__global__ __launch_bounds__(512, 2) void gemm8p(const unsigned short* __restrict__ A,
                                                 const unsigned short* __restrict__ Bw,
                                                 void* __restrict__ o0,
                                                 void* __restrict__ o1,
                                                 void* __restrict__ o2) {
  constexpr int NT = 32;                        // K/64
  constexpr int NREP = BN / 64;                 // 4 or 2
  constexpr int BBH = BN * 64;                  // B K-half bytes: 16384/8192
  constexpr int NBL = BBH / 8192;               // B loads per K-half: 2/1
  constexpr int BUFSZ = 32768 + 2 * BBH;        // 65536 / 49152
  __shared__ __align__(16) char smem[2 * BUFSZ];

  const int tid = threadIdx.x;
  const int w = tid >> 6, l = tid & 63;
  const int wm = w >> 2, wn = w & 3;

  constexpr int NBN_T = (MODE == 2) ? 12 : 16;
  const int wgid = (blockIdx.x & 7) * (NBN_T * 2) + (blockIdx.x >> 3);
  const int bm = (wgid & 15) << 8;
  const int bn = (wgid >> 4) * BN;

  // ---- staging lane constants (pre-swizzled global source; linear LDS) ----
  const int srow = tid >> 2;                                    // 0..127
  const int scb = (((tid & 3) ^ ((tid >> 3) & 3)) << 4);        // inv-swizzled col
  const char* Agp = (const char*)A + ((size_t)(bm + srow) << 12) + scb;
  const char* Bgp = (const char*)Bw + ((size_t)(bn + srow) << 12) + scb;

  auto stageA = [&](int BB, int kk, int kt) {     // 16KB K-half of A (2 loads)
#pragma unroll
    for (int c = 0; c < 2; c++)
      gload_lds16(Agp + ((size_t)(c * 128) << 12) + kt * 128 + kk * 64,
                  smem + BB + kk * 16384 + c * 8192 + tid * 16);
  };
  auto stageB = [&](int BB, int kk, int kt) {     // K-half of B (NBL loads)
#pragma unroll
    for (int c = 0; c < NBL; c++)
      gload_lds16(Bgp + ((size_t)(c * 128) << 12) + kt * 128 + kk * 64,
                  smem + BB + 32768 + kk * BBH + c * 8192 + tid * 16);
  };

  // ---- read lane constants (swizzled; frag index -> immediate offset) ----
  const int gA = (((l >> 4) ^ ((l >> 1) & 3)) << 4);
  const int laneA = (wm * 128 + (l & 15)) * 64 + gA;
  const int laneB = 32768 + (wn * (BN / 4) + (l & 15)) * 64 + gA;

  f32x4 acc[8][NREP];
#pragma unroll
  for (int m = 0; m < 8; m++)
#pragma unroll
    for (int n = 0; n < NREP; n++) acc[m][n] = f32x4{0.f, 0.f, 0.f, 0.f};

  bf16x8 af[8];
  auto loadA = [&](int BB, int kk) {
#pragma unroll
    for (int m = 0; m < 8; m++)
      af[m] = *(const bf16x8*)(smem + BB + kk * 16384 + laneA + m * 1024);
  };
  auto mma8 = [&](int c0, bf16x8 b0, bf16x8 b1) {  // 16 MFMA
    __builtin_amdgcn_s_setprio(1);
#pragma unroll
    for (int m = 0; m < 8; m++) {
      acc[m][c0] = mfma16(af[m], b0, acc[m][c0]);
      acc[m][c0 + 1] = mfma16(af[m], b1, acc[m][c0 + 1]);
    }
    __builtin_amdgcn_s_setprio(0);
  };

  auto tile = [&](int t, auto bufc) {
    constexpr int BB = decltype(bufc)::value;
    constexpr int BO = BB ^ BUFSZ;
    const bool s1 = (t + 1) < NT, s2 = (t + 2) < NT;
    bf16x8 b0, b1;
    if constexpr (BN == 256) {
      // phase 0: kk0, N-half0
      loadA(BB, 0);
      b0 = *(const bf16x8*)(smem + BB + laneB);
      b1 = *(const bf16x8*)(smem + BB + laneB + 1024);
      if (s1) stageA(BO, 1, t + 1);
      BAR();
      mma8(0, b0, b1);
      BAR();
      // phase 1: kk0, N-half1
      b0 = *(const bf16x8*)(smem + BB + laneB + 2048);
      b1 = *(const bf16x8*)(smem + BB + laneB + 3072);
      if (s1) stageB(BO, 1, t + 1);
      BAR();
      mma8(2, b0, b1);
      if (s1) { asm volatile("s_waitcnt vmcnt(8)" ::: "memory"); }
      else    { asm volatile("s_waitcnt vmcnt(0)" ::: "memory"); }
      BAR();
      // phase 2: kk1, N-half0
      loadA(BB, 1);
      b0 = *(const bf16x8*)(smem + BB + laneB + BBH);
      b1 = *(const bf16x8*)(smem + BB + laneB + BBH + 1024);
      if (s2) stageA(BB, 0, t + 2);
      BAR();
      mma8(0, b0, b1);
      BAR();
      // phase 3: kk1, N-half1
      b0 = *(const bf16x8*)(smem + BB + laneB + BBH + 2048);
      b1 = *(const bf16x8*)(smem + BB + laneB + BBH + 3072);
      if (s2) stageB(BB, 0, t + 2);
      BAR();
      mma8(2, b0, b1);
      if (s2)      { asm volatile("s_waitcnt vmcnt(8)" ::: "memory"); }
      else if (s1) { asm volatile("s_waitcnt vmcnt(4)" ::: "memory"); }
      else         { asm volatile("s_waitcnt vmcnt(0)" ::: "memory"); }
      BAR();
    } else {
      // phase 0: kk0 (all 2 n-reps)
      loadA(BB, 0);
      b0 = *(const bf16x8*)(smem + BB + laneB);
      b1 = *(const bf16x8*)(smem + BB + laneB + 1024);
      if (s1) { stageA(BO, 1, t + 1); stageB(BO, 1, t + 1); }
      BAR();
      mma8(0, b0, b1);
      if (s1) { asm volatile("s_waitcnt vmcnt(6)" ::: "memory"); }
      else    { asm volatile("s_waitcnt vmcnt(0)" ::: "memory"); }
      BAR();
      // phase 1: kk1
      loadA(BB, 1);
      b0 = *(const bf16x8*)(smem + BB + laneB + BBH);
      b1 = *(const bf16x8*)(smem + BB + laneB + BBH + 1024);
      if (s2) { stageA(BB, 0, t + 2); stageB(BB, 0, t + 2); }
      BAR();
      mma8(0, b0, b1);
      if (s2)      { asm volatile("s_waitcnt vmcnt(6)" ::: "memory"); }
      else if (s1) { asm volatile("s_waitcnt vmcnt(3)" ::: "memory"); }
      else         { asm volatile("s_waitcnt vmcnt(0)" ::: "memory"); }
      BAR();
    }
  };

  // prologue: k0(0), k1(0), k0(1) in steady-state issue order
  stageA(0, 0, 0); stageB(0, 0, 0);
  stageA(0, 1, 0); stageB(0, 1, 0);
  stageA(BUFSZ, 0, 1); stageB(BUFSZ, 0, 1);
  if constexpr (BN == 256) { asm volatile("s_waitcnt vmcnt(8)" ::: "memory"); }
  else                     { asm volatile("s_waitcnt vmcnt(6)" ::: "memory"); }
  BAR();

  for (int t = 0; t < NT; t += 2) {
    tile(t, std::integral_constant<int, 0>{});
    tile(t + 1, std::integral_constant<int, BUFSZ>{});
  }

  // ---- epilogue ----
#pragma unroll
  for (int m = 0; m < 8; m++) {
#pragma unroll
    for (int n = 0; n < NREP; n++) {
#pragma unroll
      for (int r = 0; r < 4; r++) {
        const int row = bm + wm * 128 + m * 16 + ((l >> 4) << 2) + r;
        const int col = bn + wn * (BN / 4) + n * 16 + (l & 15);
        const float v = acc[m][n][r];
        if (MODE == 1) {
          ((float*)o0)[(size_t)row * 2048 + col] = v;
        } else {
          const unsigned short q = f2bf(v);
          if (col < 2048) {
            ((unsigned short*)o0)[(size_t)row * 2048 + col] = q;
          } else if (col < 2560) {
            ((unsigned short*)o1)[(size_t)row * 512 + (col - 2048)] = q;
          } else {
            const int cv = col - 2560;
            ((unsigned short*)o2)[((size_t)(((row >> 11) * NKVc + (cv >> 7)) * HDc + (cv & 127)) << 11) +
                                  (row & 2047)] = q;
          }
        }
      }
    }
  }
}

// ---------------- K RoPE + relayout: raw[tok][kv*128+d] -> [b][kv][s][d] ----
__global__ __launch_bounds__(256) void rope_k(const unsigned short* __restrict__ raw,
                                              unsigned short* __restrict__ dst,
                                              const float* __restrict__ cosT,
                                              const float* __restrict__ sinT) {
  const int t = blockIdx.x * 256 + threadIdx.x;
  const int d = t & 63;
  const int h = (t >> 6) & 3;
  const int tok = t >> 8;
  const int b = tok >> 11, s = tok & 2047;
  const float c = cosT[(s << 6) + d];
  const float sn = sinT[(s << 6) + d];
  const size_t src = (size_t)tok * 512 + h * 128 + d;
  const float x0 = bf2f(raw[src]);
  const float x1 = bf2f(raw[src + 64]);
  const size_t db = ((size_t)(b * NKVc + h) * Sc + s) * HDc + d;
  dst[db] = f2bf(x0 * c - x1 * sn);
  dst[db + 64] = f2bf(x1 * c + x0 * sn);
}

// ---------------- causal GQA flash attention (R8 structure, unchanged) ------
__global__ __launch_bounds__(256, 2) void attn_kernel(const unsigned short* __restrict__ Qraw,
                                                      const unsigned short* __restrict__ Kr,
                                                      const unsigned short* __restrict__ Vt,
                                                      unsigned short* __restrict__ O,
                                                      const float* __restrict__ cosT,
                                                      const float* __restrict__ sinT) {
  __shared__ __align__(16) char smem[65536];

  const int tid = threadIdx.x, w = tid >> 6, l = tid & 63;
  const int lq = l & 31, lh = l >> 5;
  const int kvb = blockIdx.x & 7, p = blockIdx.x >> 3;
  const int b = kvb >> 2, kvh = kvb & 3, h = kvh * 4 + w;
  const int t0 = 63 - p, t1 = p;
  const int NIT0 = (t0 >> 1) + 1;
  const int NIT1 = (t1 >> 1) + 1;   // NIT0 + NIT1 == 33 always

  const char* Kb = (const char*)(Kr + (size_t)(b * NKVc + kvh) * Sc * HDc);
  const char* Vb = (const char*)(Vt + (size_t)(b * NKVc + kvh) * HDc * Sc);

  const int krow0 = tid >> 4;
  const int kcb = ((tid & 15) * 16) ^ ((krow0 & 7) << 4);
  const int vrow0 = tid >> 3;
  const int vcb = ((tid & 7) * 16) ^ ((vrow0 & 7) << 4);
  char* ldst = smem + tid * 16;

  auto stage = [&](int slot, int kt_) {
#pragma unroll
    for (int c = 0; c < 4; c++)
      gload_lds16(Kb + (size_t)(kt_ * 64 + krow0 + 16 * c) * 256 + kcb,
                  ldst + slot + c * 4096);
#pragma unroll
    for (int c = 0; c < 4; c++)
      gload_lds16(Vb + (size_t)(vrow0 + 32 * c) * 4096 + kt_ * 128 + vcb,
                  ldst + slot + 16384 + c * 4096);
  };

  const int swz = (l & 7) << 4;
  const int hi16 = lh << 4;
  int co[8];
#pragma unroll
  for (int kc = 0; kc < 8; kc++) co[kc] = (kc * 32 + hi16) ^ swz;
  const int kbase = lq * 256;
  const int vbase = 16384 + lq * 128;

  bf16x8 qf[8];
  auto loadQ = [&](int t) {
    const int srow = t * 32 + lq;
    const unsigned short* Qp = Qraw + ((size_t)(b * Sc + srow) << 11) + h * 128 + lh * 8;
#pragma unroll
    for (int kc = 0; kc < 4; kc++) {
      const bf16x8 vlo = *(const bf16x8*)(Qp + kc * 16);
      const bf16x8 vhi = *(const bf16x8*)(Qp + kc * 16 + 64);
      const float* cp = cosT + ((size_t)srow << 6) + kc * 16 + lh * 8;
      const float* sp = sinT + ((size_t)srow << 6) + kc * 16 + lh * 8;
      const float4 c0 = *(const float4*)cp, c1 = *(const float4*)(cp + 4);
      const float4 s0v = *(const float4*)sp, s1v = *(const float4*)(sp + 4);
      const float cs[8] = {c0.x, c0.y, c0.z, c0.w, c1.x, c1.y, c1.z, c1.w};
      const float ss[8] = {s0v.x, s0v.y, s0v.z, s0v.w, s1v.x, s1v.y, s1v.z, s1v.w};
#pragma unroll
      for (int j = 0; j < 8; j++) {
        const float xl = (float)vlo[j] * QSCALE;
        const float xh = (float)vhi[j] * QSCALE;
        qf[kc][j] = (__bf16)(xl * cs[j] - xh * ss[j]);
        qf[kc + 4][j] = (__bf16)(xh * cs[j] + xl * ss[j]);
      }
    }
  };

  f32x16 oacc[4];
#pragma unroll
  for (int d = 0; d < 4; d++)
#pragma unroll
    for (int r = 0; r < 16; r++) oacc[d][r] = 0.f;
  float m_run = -1e30f, sum_run = 0.f;

  int kt = 0, tcur = t0, nlast = NIT0 - 1, phase = 0;
  loadQ(t0);
  stage(0, 0);

  auto iter = [&](int i, auto slotc) {
    constexpr int SLOT = decltype(slotc)::value;
    if (i < 32) {
      const int ni = i + 1;
      stage(SLOT ^ 32768, ni < NIT0 ? ni : ni - NIT0);
      asm volatile("s_waitcnt vmcnt(8)" ::: "memory");
    } else {
      asm volatile("s_waitcnt vmcnt(0)" ::: "memory");
    }
    __builtin_amdgcn_s_barrier();

    f32x16 s0, s1;
#pragma unroll
    for (int r = 0; r < 16; r++) { s0[r] = 0.f; s1[r] = 0.f; }
    __builtin_amdgcn_s_setprio(1);
#pragma unroll
    for (int kc = 0; kc < 8; kc++) {
      const bf16x8 kf0 = *(const bf16x8*)(smem + SLOT + kbase + co[kc]);
      const bf16x8 kf1 = *(const bf16x8*)(smem + SLOT + 8192 + kbase + co[kc]);
      s0 = mfma32(kf0, qf[kc], s0);
      s1 = mfma32(kf1, qf[kc], s1);
    }
    __builtin_amdgcn_s_setprio(0);

    if (kt == nlast) {
      const int qpos = tcur * 32 + lq;
      const int kv0 = kt * 64 + 4 * lh;
#pragma unroll
      for (int r = 0; r < 16; r++) {
        const int kvv = kv0 + (r & 3) + 8 * (r >> 2);
        if (kvv > qpos) s0[r] = -1e30f;
        if (kvv + 32 > qpos) s1[r] = -1e30f;
      }
    }

    float q8[8];
#pragma unroll
    for (int g4 = 0; g4 < 4; g4++) {
      q8[g4] = fmaxf(fmaxf(s0[4 * g4], s0[4 * g4 + 1]), fmaxf(s0[4 * g4 + 2], s0[4 * g4 + 3]));
      q8[4 + g4] = fmaxf(fmaxf(s1[4 * g4], s1[4 * g4 + 1]), fmaxf(s1[4 * g4 + 2], s1[4 * g4 + 3]));
    }
    float mt = fmaxf(fmaxf(fmaxf(q8[0], q8[1]), fmaxf(q8[2], q8[3])),
                     fmaxf(fmaxf(q8[4], q8[5]), fmaxf(q8[6], q8[7])));
    mt = fmaxf(mt, __shfl_xor(mt, 32));
    if (!__all(mt <= m_run + DEFER_THR)) {
      const float mn = fmaxf(m_run, mt);
      const float al = exp2f(m_run - mn);
      m_run = mn;
      sum_run *= al;
#pragma unroll
      for (int d = 0; d < 4; d++)
#pragma unroll
        for (int r = 0; r < 16; r++) oacc[d][r] *= al;
    }

    float pv0[16], pv1[16];
    float sA = 0.f, sB = 0.f, sC = 0.f, sD = 0.f;
#pragma unroll
    for (int r = 0; r < 16; r += 4) {
      pv0[r] = exp2f(s0[r] - m_run);         sA += pv0[r];
      pv0[r + 1] = exp2f(s0[r + 1] - m_run); sB += pv0[r + 1];
      pv0[r + 2] = exp2f(s0[r + 2] - m_run); sC += pv0[r + 2];
      pv0[r + 3] = exp2f(s0[r + 3] - m_run); sD += pv0[r + 3];
    }
#pragma unroll
    for (int r = 0; r < 16; r += 4) {
      pv1[r] = exp2f(s1[r] - m_run);         sA += pv1[r];
      pv1[r + 1] = exp2f(s1[r + 1] - m_run); sB += pv1[r + 1];
      pv1[r + 2] = exp2f(s1[r + 2] - m_run); sC += pv1[r + 2];
      pv1[r + 3] = exp2f(s1[r + 3] - m_run); sD += pv1[r + 3];
    }
    sum_run += (sA + sB) + (sC + sD);

    bf16x8 pf0, pf1, pf2, pf3;
    {
      unsigned a0 = cvtpk(pv0[0], pv0[1]), a2 = cvtpk(pv0[4], pv0[5]);
      unsigned a1 = cvtpk(pv0[2], pv0[3]), a3 = cvtpk(pv0[6], pv0[7]);
      pswap(a0, a2); pswap(a1, a3);
      i32x4 t4 = {(int)a0, (int)a1, (int)a2, (int)a3};
      pf0 = __builtin_bit_cast(bf16x8, t4);
    }
    {
      unsigned a0 = cvtpk(pv0[8], pv0[9]), a2 = cvtpk(pv0[12], pv0[13]);
      unsigned a1 = cvtpk(pv0[10], pv0[11]), a3 = cvtpk(pv0[14], pv0[15]);
      pswap(a0, a2); pswap(a1, a3);
      i32x4 t4 = {(int)a0, (int)a1, (int)a2, (int)a3};
      pf1 = __builtin_bit_cast(bf16x8, t4);
    }
    {
      unsigned a0 = cvtpk(pv1[0], pv1[1]), a2 = cvtpk(pv1[4], pv1[5]);
      unsigned a1 = cvtpk(pv1[2], pv1[3]), a3 = cvtpk(pv1[6], pv1[7]);
      pswap(a0, a2); pswap(a1, a3);
      i32x4 t4 = {(int)a0, (int)a1, (int)a2, (int)a3};
      pf2 = __builtin_bit_cast(bf16x8, t4);
    }
    {
      unsigned a0 = cvtpk(pv1[8], pv1[9]), a2 = cvtpk(pv1[12], pv1[13]);
      unsigned a1 = cvtpk(pv1[10], pv1[11]), a3 = cvtpk(pv1[14], pv1[15]);
      pswap(a0, a2); pswap(a1, a3);
      i32x4 t4 = {(int)a0, (int)a1, (int)a2, (int)a3};
      pf3 = __builtin_bit_cast(bf16x8, t4);
    }

    __builtin_amdgcn_s_setprio(1);
#pragma unroll
    for (int d = 0; d < 4; d++) {
      oacc[d] = mfma32(*(const bf16x8*)(smem + SLOT + vbase + d * 4096 + co[0]), pf0, oacc[d]);
      oacc[d] = mfma32(*(const bf16x8*)(smem + SLOT + vbase + d * 4096 + co[1]), pf1, oacc[d]);
      oacc[d] = mfma32(*(const bf16x8*)(smem + SLOT + vbase + d * 4096 + co[2]), pf2, oacc[d]);
      oacc[d] = mfma32(*(const bf16x8*)(smem + SLOT + vbase + d * 4096 + co[3]), pf3, oacc[d]);
    }
    __builtin_amdgcn_s_setprio(0);

    asm volatile("s_waitcnt lgkmcnt(0)" ::: "memory");

    if (kt == nlast) {
      const float st = sum_run + __shfl_xor(sum_run, 32);
      const float rinv = 1.0f / st;
      unsigned short* Op = O + ((size_t)(b * Sc + tcur * 32 + lq) << 11) + h * 128 + lh * 4;
#pragma unroll
      for (int d = 0; d < 4; d++) {
#pragma unroll
        for (int rq = 0; rq < 4; rq++) {
          uint2 u2;
          u2.x = cvtpk(oacc[d][4 * rq] * rinv, oacc[d][4 * rq + 1] * rinv);
          u2.y = cvtpk(oacc[d][4 * rq + 2] * rinv, oacc[d][4 * rq + 3] * rinv);
          *(uint2*)(Op + d * 32 + rq * 8) = u2;
        }
      }
      if (phase == 0) {
        phase = 1; tcur = t1; kt = 0; nlast = NIT1 - 1;
#pragma unroll
        for (int d = 0; d < 4; d++)
#pragma unroll
          for (int r = 0; r < 16; r++) oacc[d][r] = 0.f;
        m_run = -1e30f;
        sum_run = 0.f;
        loadQ(t1);
      }
    } else {
      kt++;
    }
  };

  for (int u2i = 0; u2i < 16; ++u2i) {
    iter(2 * u2i, std::integral_constant<int, 0>{});
    iter(2 * u2i + 1, std::integral_constant<int, 32768>{});
  }
  iter(32, std::integral_constant<int, 0>{});
}

// ---------------------------------------------------------------------------
extern "C" void kernel_launch(void* const* d_in, const int* in_sizes, int n_in,
                              void* d_out, int out_size, void* d_ws, size_t ws_size,
                              hipStream_t stream) {
  (void)in_sizes; (void)n_in; (void)out_size; (void)ws_size;
  const float* X = (const float*)d_in[0];
  const float* Wq = (const float*)d_in[1];
  const float* Wk = (const float*)d_in[2];
  const float* Wv = (const float*)d_in[3];
  const float* Wo = (const float*)d_in[4];

  char* ws = (char*)d_ws;
  unsigned short* Xbf  = (unsigned short*)(ws + 0);         // 4096x2048 (16MB)
  unsigned short* Wqkv = (unsigned short*)(ws + 16777216);  // 3072x2048 (12.6MB)
  unsigned short* Wob  = (unsigned short*)(ws + 29360128);  // 2048x2048 (8MB)
  unsigned short* Qraw = (unsigned short*)(ws + 37748736);  // 4096x2048 (16MB)
  unsigned short* Kraw = (unsigned short*)(ws + 54525952);  // 4096x512  (4MB)
  unsigned short* Vt   = (unsigned short*)(ws + 58720256);  // [b][kv][d][s] (4MB)
  float*          cosT = (float*)(ws + 62914560);           // 2048x64 f32 (512KB)
  float*          sinT = (float*)(ws + 63438848);           // 2048x64 f32 (512KB)
  unsigned short* Kr   = (unsigned short*)(ws + 79691776);  // [b][kv][s][d] (4MB)
  unsigned short* Ows  = (unsigned short*)(ws + 83886080);  // 4096x2048 (16MB)

  rope_table<<<512, 256, 0, stream>>>(cosT, sinT);
  cvt_kernel<<<8192, 256, 0, stream>>>(X, Xbf, 2097152);
  cvt_weights<<<10240, 256, 0, stream>>>(Wq, Wk, Wv, Wo, Wqkv, Wob);

  gemm8p<256, 2><<<192, 512, 0, stream>>>(Xbf, Wqkv, Qraw, Kraw, Vt);

  rope_k<<<4096, 256, 0, stream>>>(Kraw, Kr, cosT, sinT);

  attn_kernel<<<256, 256, 0, stream>>>(Qraw, Kr, Vt, Ows, cosT, sinT);

  gemm8p<128, 1><<<256, 512, 0, stream>>>(Ows, Wob, d_out, nullptr, nullptr);
}

// Round 11
// 205.580 us; speedup vs baseline: 1.0823x; 1.0641x over previous
//
#include <hip/hip_runtime.h>
#include <cstdint>
#include <cstddef>
#include <type_traits>

// ---------------------------------------------------------------------------
// FlashSparseAttention: X->QKV proj -> RoPE -> causal GQA flash attn -> O proj
// B=2 S=2048 H=2048 NH=16 NKV=4 HD=128, fp32 in/out, bf16 MFMA internally.
// R11: GEMMs re-tiled for FULL chip coverage (grid 256 exactly for both):
//      QKV BM=256 x BN=192 (B staging padded to 256 rows), O-proj 256x128.
//      2-phase counted schedule: per phase {stage group -> ds_read frags ->
//      MFMA -> vmcnt(counted) -> lgkmcnt(0) -> barrier} (m230-V0 form, one
//      barrier/phase). Attention unchanged (R8 32x32 swapped-QK^T structure).
// ---------------------------------------------------------------------------

typedef __bf16 bf16x8 __attribute__((ext_vector_type(8)));
typedef float f32x4 __attribute__((ext_vector_type(4)));
typedef float f32x16 __attribute__((ext_vector_type(16)));
typedef int i32x4 __attribute__((ext_vector_type(4)));

#define DEVFN static __device__ __forceinline__

constexpr int Bc = 2, Sc = 2048, Hc = 2048, NHc = 16, NKVc = 4, HDc = 128;
constexpr float SM_SCALE = 0.08838834764831845f;   // 1/sqrt(128)
constexpr float QSCALE = 0.127517431f;             // SM_SCALE * log2(e)
constexpr float DEFER_THR = 11.0f;                 // ~8 nats in log2 domain

DEVFN unsigned short f2bf(float f) {
  __bf16 h = (__bf16)f;
  return __builtin_bit_cast(unsigned short, h);
}
DEVFN float bf2f(unsigned short s) { return __uint_as_float(((unsigned)s) << 16); }

DEVFN unsigned cvtpk(float lo, float hi) {
  unsigned r;
  asm("v_cvt_pk_bf16_f32 %0, %1, %2" : "=v"(r) : "v"(lo), "v"(hi));
  return r;
}
DEVFN void pswap(unsigned& x, unsigned& y) {
  asm("v_permlane32_swap_b32 %0, %1" : "+v"(x), "+v"(y));
}

DEVFN f32x16 mfma32(bf16x8 a, bf16x8 b, f32x16 c) {
  return __builtin_amdgcn_mfma_f32_32x32x16_bf16(a, b, c, 0, 0, 0);
}
DEVFN f32x4 mfma16(bf16x8 a, bf16x8 b, f32x4 c) {
  return __builtin_amdgcn_mfma_f32_16x16x32_bf16(a, b, c, 0, 0, 0);
}

DEVFN void gload_lds16(const void* g, void* l) {
  __builtin_amdgcn_global_load_lds(
      (const __attribute__((address_space(1))) unsigned int*)g,
      (__attribute__((address_space(3))) unsigned int*)l, 16, 0, 0);
}

#define BAR() __builtin_amdgcn_s_barrier()

// ---------------- fp32 -> bf16 conversion (vectorized x4) ------------------
__global__ __launch_bounds__(256) void cvt_kernel(const float* __restrict__ in,
                                                  unsigned short* __restrict__ out,
                                                  int n4) {
  int i = blockIdx.x * 256 + threadIdx.x;
  if (i >= n4) return;
  float4 v = reinterpret_cast<const float4*>(in)[i];
  ushort4 o;
  o.x = f2bf(v.x); o.y = f2bf(v.y); o.z = f2bf(v.z); o.w = f2bf(v.w);
  reinterpret_cast<ushort4*>(out)[i] = o;
}

// ---------------- fused weight conversion (Wq|Wk|Wv -> Wqkv, Wo -> Wob) ----
__global__ __launch_bounds__(256) void cvt_weights(const float* __restrict__ Wq,
                                                   const float* __restrict__ Wk,
                                                   const float* __restrict__ Wv,
                                                   const float* __restrict__ Wo,
                                                   unsigned short* __restrict__ Wqkv,
                                                   unsigned short* __restrict__ Wob) {
  const int i = blockIdx.x * 256 + threadIdx.x;  // float4 index, total 2621440
  const float* src;
  unsigned short* dst;
  int off;
  if (i < 1048576) { src = Wq; dst = Wqkv; off = i; }
  else if (i < 1310720) { src = Wk; dst = Wqkv + 4194304; off = i - 1048576; }
  else if (i < 1572864) { src = Wv; dst = Wqkv + 5242880; off = i - 1310720; }
  else { src = Wo; dst = Wob; off = i - 1572864; }
  float4 v = reinterpret_cast<const float4*>(src)[off];
  ushort4 o;
  o.x = f2bf(v.x); o.y = f2bf(v.y); o.z = f2bf(v.z); o.w = f2bf(v.w);
  reinterpret_cast<ushort4*>(dst)[off] = o;
}

// ---------------- RoPE cos/sin table: [s][d] d in 0..63, f32 ---------------
__global__ __launch_bounds__(256) void rope_table(float* __restrict__ cosT,
                                                  float* __restrict__ sinT) {
  const int i = blockIdx.x * 256 + threadIdx.x;  // 131072 = 2048*64
  const int s = i >> 6, d = i & 63;
  const float inv = exp2f(-0.2076205059304601f * (float)d);  // 10000^(-d/64)
  float sn, c;
  sincosf((float)s * inv, &sn, &c);
  cosT[i] = c;
  sinT[i] = sn;
}

// ---------------- 2-phase counted NT GEMM (BM=256, BK=64, grid 256) ---------
// 8 waves (2M x 4N, 512 thr). LDS: 2 buffers, each = A[2kk][256 rows x 64B] +
// B[2kk][256(padded) rows x 64B], swizzle g16 ^= (row>>1)&3 both-sides.
// Per phase (kk half): stage one K-half group of a future tile -> ds_read
// frags -> MFMA cluster -> vmcnt(counted) -> lgkmcnt(0) -> s_barrier.
// Steady 3 groups in flight; audited waits: VS=2*(2+NBL), tails G and 0.
// BN=192: NREP=3 (B staging reads 256 rows, 64 overshoot rows land in the
// next ws buffer - defined memory, never read back). BN=128: NREP=2.
// MODE 2: fused QKV epilogue; MODE 1: f32 out.
template <int BN, int MODE>
__global__ __launch_bounds__(512, 2) void gemm2p(const unsigned short* __restrict__ A,
                                                 const unsigned short* __restrict__ Bw,
                                                 void* __restrict__ o0,
                                                 void* __restrict__ o1,
                                                 void* __restrict__ o2) {
  constexpr int NT = 32;                       // K/64
  constexpr int NREP = BN / 64;                // 3 or 2
  constexpr int NBL = (BN == 192) ? 2 : 1;     // B loads per K-half
  constexpr int BBH = NBL * 8192;              // B K-half bytes (padded)
  constexpr int BUFSZ = 32768 + 2 * BBH;       // 65536 / 49152
  constexpr int G = 2 + NBL;                   // loads per K-half group
  __shared__ __align__(16) char smem[2 * BUFSZ];

  const int tid = threadIdx.x;
  const int w = tid >> 6, l = tid & 63;
  const int wm = w >> 2, wn = w & 3;

  // XCD swizzle; grid = 256 = 16 row-tiles x 16 col-tiles
  const int wgid = (blockIdx.x & 7) * 32 + (blockIdx.x >> 3);
  const int bm = (wgid & 15) << 8;
  const int bn = (wgid >> 4) * BN;

  // staging lane constants (pre-swizzled global source; linear LDS dest)
  const int srow = tid >> 2;                                   // 0..127
  const int scb = (((tid & 3) ^ ((tid >> 3) & 3)) << 4);
  const char* Agp = (const char*)A + ((size_t)(bm + srow) << 12) + scb;
  const char* Bgp = (const char*)Bw + ((size_t)(bn + srow) << 12) + scb;

  auto stageG = [&](int BB, int kk, int kt) {    // one K-half group (A + B)
#pragma unroll
    for (int c = 0; c < 2; c++)
      gload_lds16(Agp + ((size_t)(c * 128) << 12) + kt * 128 + kk * 64,
                  smem + BB + kk * 16384 + c * 8192 + tid * 16);
#pragma unroll
    for (int c = 0; c < NBL; c++)
      gload_lds16(Bgp + ((size_t)(c * 128) << 12) + kt * 128 + kk * 64,
                  smem + BB + 32768 + kk * BBH + c * 8192 + tid * 16);
  };

  // read lane constants (swizzled; frag -> +1024B immediate)
  const int gA = (((l >> 4) ^ ((l >> 1) & 3)) << 4);
  const int laneA = (wm * 128 + (l & 15)) * 64 + gA;
  const int laneB = 32768 + (wn * (BN / 4) + (l & 15)) * 64 + gA;

  f32x4 acc[8][NREP];
#pragma unroll
  for (int m = 0; m < 8; m++)
#pragma unroll
    for (int n = 0; n < NREP; n++) acc[m][n] = f32x4{0.f, 0.f, 0.f, 0.f};

  // prologue: G(buf0,kk0,0), G(buf0,kk1,0), G(buf1,kk0,1)
  stageG(0, 0, 0);
  stageG(0, 1, 0);
  stageG(BUFSZ, 0, 1);
  asm volatile("s_waitcnt vmcnt(%0)" ::"n"(2 * G) : "memory");
  BAR();

  auto phase = [&](int t, int kk, auto bufc) {
    constexpr int BB = decltype(bufc)::value;
    constexpr int BO = BB ^ BUFSZ;
    // stage one group of a future K-half
    if (kk == 0) {
      if (t + 1 < NT) stageG(BO, 1, t + 1);
    } else {
      if (t + 2 < NT) stageG(BB, 0, t + 2);
    }
    // ds_read current frags
    bf16x8 af[8], bfr[NREP];
#pragma unroll
    for (int m = 0; m < 8; m++)
      af[m] = *(const bf16x8*)(smem + BB + kk * 16384 + laneA + m * 1024);
#pragma unroll
    for (int n = 0; n < NREP; n++)
      bfr[n] = *(const bf16x8*)(smem + BB + kk * BBH + laneB + n * 1024);
    // MFMA cluster
    __builtin_amdgcn_s_setprio(1);
#pragma unroll
    for (int m = 0; m < 8; m++)
#pragma unroll
      for (int n = 0; n < NREP; n++)
        acc[m][n] = mfma16(af[m], bfr[n], acc[m][n]);
    __builtin_amdgcn_s_setprio(0);
    // counted vmcnt (audited): next phase's source group must have landed
    if (kk == 0) {
      if (t + 1 < NT) { asm volatile("s_waitcnt vmcnt(%0)" ::"n"(2 * G) : "memory"); }
      else            { asm volatile("s_waitcnt vmcnt(0)" ::: "memory"); }
    } else {
      if (t + 2 < NT)      { asm volatile("s_waitcnt vmcnt(%0)" ::"n"(2 * G) : "memory"); }
      else if (t + 1 < NT) { asm volatile("s_waitcnt vmcnt(%0)" ::"n"(G) : "memory"); }
    }
    asm volatile("s_waitcnt lgkmcnt(0)" ::: "memory");  // reads drained (free)
    BAR();
  };

  for (int t = 0; t < NT; t += 2) {
    phase(t, 0, std::integral_constant<int, 0>{});
    phase(t, 1, std::integral_constant<int, 0>{});
    phase(t + 1, 0, std::integral_constant<int, BUFSZ>{});
    phase(t + 1, 1, std::integral_constant<int, BUFSZ>{});
  }

  // ---- epilogue ----
#pragma unroll
  for (int m = 0; m < 8; m++) {
#pragma unroll
    for (int n = 0; n < NREP; n++) {
#pragma unroll
      for (int r = 0; r < 4; r++) {
        const int row = bm + wm * 128 + m * 16 + ((l >> 4) << 2) + r;
        const int col = bn + wn * (BN / 4) + n * 16 + (l & 15);
        const float v = acc[m][n][r];
        if (MODE == 1) {
          ((float*)o0)[(size_t)row * 2048 + col] = v;
        } else {
          const unsigned short q = f2bf(v);
          if (col < 2048) {
            ((unsigned short*)o0)[(size_t)row * 2048 + col] = q;
          } else if (col < 2560) {
            ((unsigned short*)o1)[(size_t)row * 512 + (col - 2048)] = q;
          } else {
            const int cv = col - 2560;
            ((unsigned short*)o2)[((size_t)(((row >> 11) * NKVc + (cv >> 7)) * HDc + (cv & 127)) << 11) +
                                  (row & 2047)] = q;
          }
        }
      }
    }
  }
}

// ---------------- K RoPE + relayout: raw[tok][kv*128+d] -> [b][kv][s][d] ----
__global__ __launch_bounds__(256) void rope_k(const unsigned short* __restrict__ raw,
                                              unsigned short* __restrict__ dst,
                                              const float* __restrict__ cosT,
                                              const float* __restrict__ sinT) {
  const int t = blockIdx.x * 256 + threadIdx.x;
  const int d = t & 63;
  const int h = (t >> 6) & 3;
  const int tok = t >> 8;
  const int b = tok >> 11, s = tok & 2047;
  const float c = cosT[(s << 6) + d];
  const float sn = sinT[(s << 6) + d];
  const size_t src = (size_t)tok * 512 + h * 128 + d;
  const float x0 = bf2f(raw[src]);
  const float x1 = bf2f(raw[src + 64]);
  const size_t db = ((size_t)(b * NKVc + h) * Sc + s) * HDc + d;
  dst[db] = f2bf(x0 * c - x1 * sn);
  dst[db + 64] = f2bf(x1 * c + x0 * sn);
}

// ---------------- causal GQA flash attention (R8 structure, unchanged) ------
__global__ __launch_bounds__(256, 2) void attn_kernel(const unsigned short* __restrict__ Qraw,
                                                      const unsigned short* __restrict__ Kr,
                                                      const unsigned short* __restrict__ Vt,
                                                      unsigned short* __restrict__ O,
                                                      const float* __restrict__ cosT,
                                                      const float* __restrict__ sinT) {
  __shared__ __align__(16) char smem[65536];

  const int tid = threadIdx.x, w = tid >> 6, l = tid & 63;
  const int lq = l & 31, lh = l >> 5;
  const int kvb = blockIdx.x & 7, p = blockIdx.x >> 3;
  const int b = kvb >> 2, kvh = kvb & 3, h = kvh * 4 + w;
  const int t0 = 63 - p, t1 = p;
  const int NIT0 = (t0 >> 1) + 1;
  const int NIT1 = (t1 >> 1) + 1;   // NIT0 + NIT1 == 33 always

  const char* Kb = (const char*)(Kr + (size_t)(b * NKVc + kvh) * Sc * HDc);
  const char* Vb = (const char*)(Vt + (size_t)(b * NKVc + kvh) * HDc * Sc);

  const int krow0 = tid >> 4;
  const int kcb = ((tid & 15) * 16) ^ ((krow0 & 7) << 4);
  const int vrow0 = tid >> 3;
  const int vcb = ((tid & 7) * 16) ^ ((vrow0 & 7) << 4);
  char* ldst = smem + tid * 16;

  auto stage = [&](int slot, int kt_) {
#pragma unroll
    for (int c = 0; c < 4; c++)
      gload_lds16(Kb + (size_t)(kt_ * 64 + krow0 + 16 * c) * 256 + kcb,
                  ldst + slot + c * 4096);
#pragma unroll
    for (int c = 0; c < 4; c++)
      gload_lds16(Vb + (size_t)(vrow0 + 32 * c) * 4096 + kt_ * 128 + vcb,
                  ldst + slot + 16384 + c * 4096);
  };

  const int swz = (l & 7) << 4;
  const int hi16 = lh << 4;
  int co[8];
#pragma unroll
  for (int kc = 0; kc < 8; kc++) co[kc] = (kc * 32 + hi16) ^ swz;
  const int kbase = lq * 256;
  const int vbase = 16384 + lq * 128;

  bf16x8 qf[8];
  auto loadQ = [&](int t) {
    const int srow = t * 32 + lq;
    const unsigned short* Qp = Qraw + ((size_t)(b * Sc + srow) << 11) + h * 128 + lh * 8;
#pragma unroll
    for (int kc = 0; kc < 4; kc++) {
      const bf16x8 vlo = *(const bf16x8*)(Qp + kc * 16);
      const bf16x8 vhi = *(const bf16x8*)(Qp + kc * 16 + 64);
      const float* cp = cosT + ((size_t)srow << 6) + kc * 16 + lh * 8;
      const float* sp = sinT + ((size_t)srow << 6) + kc * 16 + lh * 8;
      const float4 c0 = *(const float4*)cp, c1 = *(const float4*)(cp + 4);
      const float4 s0v = *(const float4*)sp, s1v = *(const float4*)(sp + 4);
      const float cs[8] = {c0.x, c0.y, c0.z, c0.w, c1.x, c1.y, c1.z, c1.w};
      const float ss[8] = {s0v.x, s0v.y, s0v.z, s0v.w, s1v.x, s1v.y, s1v.z, s1v.w};
#pragma unroll
      for (int j = 0; j < 8; j++) {
        const float xl = (float)vlo[j] * QSCALE;
        const float xh = (float)vhi[j] * QSCALE;
        qf[kc][j] = (__bf16)(xl * cs[j] - xh * ss[j]);
        qf[kc + 4][j] = (__bf16)(xh * cs[j] + xl * ss[j]);
      }
    }
  };

  f32x16 oacc[4];
#pragma unroll
  for (int d = 0; d < 4; d++)
#pragma unroll
    for (int r = 0; r < 16; r++) oacc[d][r] = 0.f;
  float m_run = -1e30f, sum_run = 0.f;

  int kt = 0, tcur = t0, nlast = NIT0 - 1, phase = 0;
  loadQ(t0);
  stage(0, 0);

  auto iter = [&](int i, auto slotc) {
    constexpr int SLOT = decltype(slotc)::value;
    if (i < 32) {
      const int ni = i + 1;
      stage(SLOT ^ 32768, ni < NIT0 ? ni : ni - NIT0);
      asm volatile("s_waitcnt vmcnt(8)" ::: "memory");
    } else {
      asm volatile("s_waitcnt vmcnt(0)" ::: "memory");
    }
    __builtin_amdgcn_s_barrier();

    f32x16 s0, s1;
#pragma unroll
    for (int r = 0; r < 16; r++) { s0[r] = 0.f; s1[r] = 0.f; }
    __builtin_amdgcn_s_setprio(1);
#pragma unroll
    for (int kc = 0; kc < 8; kc++) {
      const bf16x8 kf0 = *(const bf16x8*)(smem + SLOT + kbase + co[kc]);
      const bf16x8 kf1 = *(const bf16x8*)(smem + SLOT + 8192 + kbase + co[kc]);
      s0 = mfma32(kf0, qf[kc], s0);
      s1 = mfma32(kf1, qf[kc], s1);
    }
    __builtin_amdgcn_s_setprio(0);

    if (kt == nlast) {
      const int qpos = tcur * 32 + lq;
      const int kv0 = kt * 64 + 4 * lh;
#pragma unroll
      for (int r = 0; r < 16; r++) {
        const int kvv = kv0 + (r & 3) + 8 * (r >> 2);
        if (kvv > qpos) s0[r] = -1e30f;
        if (kvv + 32 > qpos) s1[r] = -1e30f;
      }
    }

    float q8[8];
#pragma unroll
    for (int g4 = 0; g4 < 4; g4++) {
      q8[g4] = fmaxf(fmaxf(s0[4 * g4], s0[4 * g4 + 1]), fmaxf(s0[4 * g4 + 2], s0[4 * g4 + 3]));
      q8[4 + g4] = fmaxf(fmaxf(s1[4 * g4], s1[4 * g4 + 1]), fmaxf(s1[4 * g4 + 2], s1[4 * g4 + 3]));
    }
    float mt = fmaxf(fmaxf(fmaxf(q8[0], q8[1]), fmaxf(q8[2], q8[3])),
                     fmaxf(fmaxf(q8[4], q8[5]), fmaxf(q8[6], q8[7])));
    mt = fmaxf(mt, __shfl_xor(mt, 32));
    if (!__all(mt <= m_run + DEFER_THR)) {
      const float mn = fmaxf(m_run, mt);
      const float al = exp2f(m_run - mn);
      m_run = mn;
      sum_run *= al;
#pragma unroll
      for (int d = 0; d < 4; d++)
#pragma unroll
        for (int r = 0; r < 16; r++) oacc[d][r] *= al;
    }

    float pv0[16], pv1[16];
    float sA = 0.f, sB = 0.f, sC = 0.f, sD = 0.f;
#pragma unroll
    for (int r = 0; r < 16; r += 4) {
      pv0[r] = exp2f(s0[r] - m_run);         sA += pv0[r];
      pv0[r + 1] = exp2f(s0[r + 1] - m_run); sB += pv0[r + 1];
      pv0[r + 2] = exp2f(s0[r + 2] - m_run); sC += pv0[r + 2];
      pv0[r + 3] = exp2f(s0[r + 3] - m_run); sD += pv0[r + 3];
    }
#pragma unroll
    for (int r = 0; r < 16; r += 4) {
      pv1[r] = exp2f(s1[r] - m_run);         sA += pv1[r];
      pv1[r + 1] = exp2f(s1[r + 1] - m_run); sB += pv1[r + 1];
      pv1[r + 2] = exp2f(s1[r + 2] - m_run); sC += pv1[r + 2];
      pv1[r + 3] = exp2f(s1[r + 3] - m_run); sD += pv1[r + 3];
    }
    sum_run += (sA + sB) + (sC + sD);

    bf16x8 pf0, pf1, pf2, pf3;
    {
      unsigned a0 = cvtpk(pv0[0], pv0[1]), a2 = cvtpk(pv0[4], pv0[5]);
      unsigned a1 = cvtpk(pv0[2], pv0[3]), a3 = cvtpk(pv0[6], pv0[7]);
      pswap(a0, a2); pswap(a1, a3);
      i32x4 t4 = {(int)a0, (int)a1, (int)a2, (int)a3};
      pf0 = __builtin_bit_cast(bf16x8, t4);
    }
    {
      unsigned a0 = cvtpk(pv0[8], pv0[9]), a2 = cvtpk(pv0[12], pv0[13]);
      unsigned a1 = cvtpk(pv0[10], pv0[11]), a3 = cvtpk(pv0[14], pv0[15]);
      pswap(a0, a2); pswap(a1, a3);
      i32x4 t4 = {(int)a0, (int)a1, (int)a2, (int)a3};
      pf1 = __builtin_bit_cast(bf16x8, t4);
    }
    {
      unsigned a0 = cvtpk(pv1[0], pv1[1]), a2 = cvtpk(pv1[4], pv1[5]);
      unsigned a1 = cvtpk(pv1[2], pv1[3]), a3 = cvtpk(pv1[6], pv1[7]);
      pswap(a0, a2); pswap(a1, a3);
      i32x4 t4 = {(int)a0, (int)a1, (int)a2, (int)a3};
      pf2 = __builtin_bit_cast(bf16x8, t4);
    }
    {
      unsigned a0 = cvtpk(pv1[8], pv1[9]), a2 = cvtpk(pv1[12], pv1[13]);
      unsigned a1 = cvtpk(pv1[10], pv1[11]), a3 = cvtpk(pv1[14], pv1[15]);
      pswap(a0, a2); pswap(a1, a3);
      i32x4 t4 = {(int)a0, (int)a1, (int)a2, (int)a3};
      pf3 = __builtin_bit_cast(bf16x8, t4);
    }

    __builtin_amdgcn_s_setprio(1);
#pragma unroll
    for (int d = 0; d < 4; d++) {
      oacc[d] = mfma32(*(const bf16x8*)(smem + SLOT + vbase + d * 4096 + co[0]), pf0, oacc[d]);
      oacc[d] = mfma32(*(const bf16x8*)(smem + SLOT + vbase + d * 4096 + co[1]), pf1, oacc[d]);
      oacc[d] = mfma32(*(const bf16x8*)(smem + SLOT + vbase + d * 4096 + co[2]), pf2, oacc[d]);
      oacc[d] = mfma32(*(const bf16x8*)(smem + SLOT + vbase + d * 4096 + co[3]), pf3, oacc[d]);
    }
    __builtin_amdgcn_s_setprio(0);

    asm volatile("s_waitcnt lgkmcnt(0)" ::: "memory");

    if (kt == nlast) {
      const float st = sum_run + __shfl_xor(sum_run, 32);
      const float rinv = 1.0f / st;
      unsigned short* Op = O + ((size_t)(b * Sc + tcur * 32 + lq) << 11) + h * 128 + lh * 4;
#pragma unroll
      for (int d = 0; d < 4; d++) {
#pragma unroll
        for (int rq = 0; rq < 4; rq++) {
          uint2 u2;
          u2.x = cvtpk(oacc[d][4 * rq] * rinv, oacc[d][4 * rq + 1] * rinv);
          u2.y = cvtpk(oacc[d][4 * rq + 2] * rinv, oacc[d][4 * rq + 3] * rinv);
          *(uint2*)(Op + d * 32 + rq * 8) = u2;
        }
      }
      if (phase == 0) {
        phase = 1; tcur = t1; kt = 0; nlast = NIT1 - 1;
#pragma unroll
        for (int d = 0; d < 4; d++)
#pragma unroll
          for (int r = 0; r < 16; r++) oacc[d][r] = 0.f;
        m_run = -1e30f;
        sum_run = 0.f;
        loadQ(t1);
      }
    } else {
      kt++;
    }
  };

  for (int u2i = 0; u2i < 16; ++u2i) {
    iter(2 * u2i, std::integral_constant<int, 0>{});
    iter(2 * u2i + 1, std::integral_constant<int, 32768>{});
  }
  iter(32, std::integral_constant<int, 0>{});
}

// ---------------------------------------------------------------------------
extern "C" void kernel_launch(void* const* d_in, const int* in_sizes, int n_in,
                              void* d_out, int out_size, void* d_ws, size_t ws_size,
                              hipStream_t stream) {
  (void)in_sizes; (void)n_in; (void)out_size; (void)ws_size;
  const float* X = (const float*)d_in[0];
  const float* Wq = (const float*)d_in[1];
  const float* Wk = (const float*)d_in[2];
  const float* Wv = (const float*)d_in[3];
  const float* Wo = (const float*)d_in[4];

  char* ws = (char*)d_ws;
  unsigned short* Xbf  = (unsigned short*)(ws + 0);         // 4096x2048 (16MB)
  unsigned short* Wqkv = (unsigned short*)(ws + 16777216);  // 3072x2048 (12.6MB)
  unsigned short* Wob  = (unsigned short*)(ws + 29360128);  // 2048x2048 (8MB)
  unsigned short* Qraw = (unsigned short*)(ws + 37748736);  // 4096x2048 (16MB)
  unsigned short* Kraw = (unsigned short*)(ws + 54525952);  // 4096x512  (4MB)
  unsigned short* Vt   = (unsigned short*)(ws + 58720256);  // [b][kv][d][s] (4MB)
  float*          cosT = (float*)(ws + 62914560);           // 2048x64 f32 (512KB)
  float*          sinT = (float*)(ws + 63438848);           // 2048x64 f32 (512KB)
  unsigned short* Kr   = (unsigned short*)(ws + 79691776);  // [b][kv][s][d] (4MB)
  unsigned short* Ows  = (unsigned short*)(ws + 83886080);  // 4096x2048 (16MB)

  rope_table<<<512, 256, 0, stream>>>(cosT, sinT);
  cvt_kernel<<<8192, 256, 0, stream>>>(X, Xbf, 2097152);
  cvt_weights<<<10240, 256, 0, stream>>>(Wq, Wk, Wv, Wo, Wqkv, Wob);

  gemm2p<192, 2><<<256, 512, 0, stream>>>(Xbf, Wqkv, Qraw, Kraw, Vt);

  rope_k<<<4096, 256, 0, stream>>>(Kraw, Kr, cosT, sinT);

  attn_kernel<<<256, 256, 0, stream>>>(Qraw, Kr, Vt, Ows, cosT, sinT);

  gemm2p<128, 1><<<256, 512, 0, stream>>>(Ows, Wob, d_out, nullptr, nullptr);
}

// Round 12
// 202.771 us; speedup vs baseline: 1.0973x; 1.0139x over previous
//
#include <hip/hip_runtime.h>
#include <cstdint>
#include <cstddef>
#include <type_traits>

// ---------------------------------------------------------------------------
// FlashSparseAttention: X->QKV proj -> RoPE -> causal GQA flash attn -> O proj
// B=2 S=2048 H=2048 NH=16 NKV=4 HD=128, fp32 in/out, bf16 MFMA internally.
// R12: attn de-paired -> grid 512 (one q-tile/block, t = u<32 ? 63-u : u-32).
//      Pairs (bid, bid+256) have NIT sums of exactly 33 and co-reside on the
//      same CU under ordered dispatch -> 2 blocks/CU = 8 waves/CU (was 4),
//      cross-block overlap replaces the dead single-block barrier coupling.
//      Kernel math identical to R8/R11. GEMMs unchanged (R11 gemm2p).
// ---------------------------------------------------------------------------

typedef __bf16 bf16x8 __attribute__((ext_vector_type(8)));
typedef float f32x4 __attribute__((ext_vector_type(4)));
typedef float f32x16 __attribute__((ext_vector_type(16)));
typedef int i32x4 __attribute__((ext_vector_type(4)));

#define DEVFN static __device__ __forceinline__

constexpr int Bc = 2, Sc = 2048, Hc = 2048, NHc = 16, NKVc = 4, HDc = 128;
constexpr float SM_SCALE = 0.08838834764831845f;   // 1/sqrt(128)
constexpr float QSCALE = 0.127517431f;             // SM_SCALE * log2(e)
constexpr float DEFER_THR = 11.0f;                 // ~8 nats in log2 domain

DEVFN unsigned short f2bf(float f) {
  __bf16 h = (__bf16)f;
  return __builtin_bit_cast(unsigned short, h);
}
DEVFN float bf2f(unsigned short s) { return __uint_as_float(((unsigned)s) << 16); }

DEVFN unsigned cvtpk(float lo, float hi) {
  unsigned r;
  asm("v_cvt_pk_bf16_f32 %0, %1, %2" : "=v"(r) : "v"(lo), "v"(hi));
  return r;
}
DEVFN void pswap(unsigned& x, unsigned& y) {
  asm("v_permlane32_swap_b32 %0, %1" : "+v"(x), "+v"(y));
}

DEVFN f32x16 mfma32(bf16x8 a, bf16x8 b, f32x16 c) {
  return __builtin_amdgcn_mfma_f32_32x32x16_bf16(a, b, c, 0, 0, 0);
}
DEVFN f32x4 mfma16(bf16x8 a, bf16x8 b, f32x4 c) {
  return __builtin_amdgcn_mfma_f32_16x16x32_bf16(a, b, c, 0, 0, 0);
}

DEVFN void gload_lds16(const void* g, void* l) {
  __builtin_amdgcn_global_load_lds(
      (const __attribute__((address_space(1))) unsigned int*)g,
      (__attribute__((address_space(3))) unsigned int*)l, 16, 0, 0);
}

#define BAR() __builtin_amdgcn_s_barrier()

// ---------------- fp32 -> bf16 conversion (vectorized x4) ------------------
__global__ __launch_bounds__(256) void cvt_kernel(const float* __restrict__ in,
                                                  unsigned short* __restrict__ out,
                                                  int n4) {
  int i = blockIdx.x * 256 + threadIdx.x;
  if (i >= n4) return;
  float4 v = reinterpret_cast<const float4*>(in)[i];
  ushort4 o;
  o.x = f2bf(v.x); o.y = f2bf(v.y); o.z = f2bf(v.z); o.w = f2bf(v.w);
  reinterpret_cast<ushort4*>(out)[i] = o;
}

// ---------------- fused weight conversion (Wq|Wk|Wv -> Wqkv, Wo -> Wob) ----
__global__ __launch_bounds__(256) void cvt_weights(const float* __restrict__ Wq,
                                                   const float* __restrict__ Wk,
                                                   const float* __restrict__ Wv,
                                                   const float* __restrict__ Wo,
                                                   unsigned short* __restrict__ Wqkv,
                                                   unsigned short* __restrict__ Wob) {
  const int i = blockIdx.x * 256 + threadIdx.x;  // float4 index, total 2621440
  const float* src;
  unsigned short* dst;
  int off;
  if (i < 1048576) { src = Wq; dst = Wqkv; off = i; }
  else if (i < 1310720) { src = Wk; dst = Wqkv + 4194304; off = i - 1048576; }
  else if (i < 1572864) { src = Wv; dst = Wqkv + 5242880; off = i - 1310720; }
  else { src = Wo; dst = Wob; off = i - 1572864; }
  float4 v = reinterpret_cast<const float4*>(src)[off];
  ushort4 o;
  o.x = f2bf(v.x); o.y = f2bf(v.y); o.z = f2bf(v.z); o.w = f2bf(v.w);
  reinterpret_cast<ushort4*>(dst)[off] = o;
}

// ---------------- RoPE cos/sin table: [s][d] d in 0..63, f32 ---------------
__global__ __launch_bounds__(256) void rope_table(float* __restrict__ cosT,
                                                  float* __restrict__ sinT) {
  const int i = blockIdx.x * 256 + threadIdx.x;  // 131072 = 2048*64
  const int s = i >> 6, d = i & 63;
  const float inv = exp2f(-0.2076205059304601f * (float)d);  // 10000^(-d/64)
  float sn, c;
  sincosf((float)s * inv, &sn, &c);
  cosT[i] = c;
  sinT[i] = sn;
}

// ---------------- 2-phase counted NT GEMM (BM=256, BK=64, grid 256) ---------
template <int BN, int MODE>
__global__ __launch_bounds__(512, 2) void gemm2p(const unsigned short* __restrict__ A,
                                                 const unsigned short* __restrict__ Bw,
                                                 void* __restrict__ o0,
                                                 void* __restrict__ o1,
                                                 void* __restrict__ o2) {
  constexpr int NT = 32;                       // K/64
  constexpr int NREP = BN / 64;                // 3 or 2
  constexpr int NBL = (BN == 192) ? 2 : 1;     // B loads per K-half
  constexpr int BBH = NBL * 8192;              // B K-half bytes (padded)
  constexpr int BUFSZ = 32768 + 2 * BBH;       // 65536 / 49152
  constexpr int G = 2 + NBL;                   // loads per K-half group
  __shared__ __align__(16) char smem[2 * BUFSZ];

  const int tid = threadIdx.x;
  const int w = tid >> 6, l = tid & 63;
  const int wm = w >> 2, wn = w & 3;

  const int wgid = (blockIdx.x & 7) * 32 + (blockIdx.x >> 3);
  const int bm = (wgid & 15) << 8;
  const int bn = (wgid >> 4) * BN;

  const int srow = tid >> 2;                                   // 0..127
  const int scb = (((tid & 3) ^ ((tid >> 3) & 3)) << 4);
  const char* Agp = (const char*)A + ((size_t)(bm + srow) << 12) + scb;
  const char* Bgp = (const char*)Bw + ((size_t)(bn + srow) << 12) + scb;

  auto stageG = [&](int BB, int kk, int kt) {    // one K-half group (A + B)
#pragma unroll
    for (int c = 0; c < 2; c++)
      gload_lds16(Agp + ((size_t)(c * 128) << 12) + kt * 128 + kk * 64,
                  smem + BB + kk * 16384 + c * 8192 + tid * 16);
#pragma unroll
    for (int c = 0; c < NBL; c++)
      gload_lds16(Bgp + ((size_t)(c * 128) << 12) + kt * 128 + kk * 64,
                  smem + BB + 32768 + kk * BBH + c * 8192 + tid * 16);
  };

  const int gA = (((l >> 4) ^ ((l >> 1) & 3)) << 4);
  const int laneA = (wm * 128 + (l & 15)) * 64 + gA;
  const int laneB = 32768 + (wn * (BN / 4) + (l & 15)) * 64 + gA;

  f32x4 acc[8][NREP];
#pragma unroll
  for (int m = 0; m < 8; m++)
#pragma unroll
    for (int n = 0; n < NREP; n++) acc[m][n] = f32x4{0.f, 0.f, 0.f, 0.f};

  stageG(0, 0, 0);
  stageG(0, 1, 0);
  stageG(BUFSZ, 0, 1);
  asm volatile("s_waitcnt vmcnt(%0)" ::"n"(2 * G) : "memory");
  BAR();

  auto phase = [&](int t, int kk, auto bufc) {
    constexpr int BB = decltype(bufc)::value;
    constexpr int BO = BB ^ BUFSZ;
    if (kk == 0) {
      if (t + 1 < NT) stageG(BO, 1, t + 1);
    } else {
      if (t + 2 < NT) stageG(BB, 0, t + 2);
    }
    bf16x8 af[8], bfr[NREP];
#pragma unroll
    for (int m = 0; m < 8; m++)
      af[m] = *(const bf16x8*)(smem + BB + kk * 16384 + laneA + m * 1024);
#pragma unroll
    for (int n = 0; n < NREP; n++)
      bfr[n] = *(const bf16x8*)(smem + BB + kk * BBH + laneB + n * 1024);
    __builtin_amdgcn_s_setprio(1);
#pragma unroll
    for (int m = 0; m < 8; m++)
#pragma unroll
      for (int n = 0; n < NREP; n++)
        acc[m][n] = mfma16(af[m], bfr[n], acc[m][n]);
    __builtin_amdgcn_s_setprio(0);
    if (kk == 0) {
      if (t + 1 < NT) { asm volatile("s_waitcnt vmcnt(%0)" ::"n"(2 * G) : "memory"); }
      else            { asm volatile("s_waitcnt vmcnt(0)" ::: "memory"); }
    } else {
      if (t + 2 < NT)      { asm volatile("s_waitcnt vmcnt(%0)" ::"n"(2 * G) : "memory"); }
      else if (t + 1 < NT) { asm volatile("s_waitcnt vmcnt(%0)" ::"n"(G) : "memory"); }
    }
    asm volatile("s_waitcnt lgkmcnt(0)" ::: "memory");
    BAR();
  };

  for (int t = 0; t < NT; t += 2) {
    phase(t, 0, std::integral_constant<int, 0>{});
    phase(t, 1, std::integral_constant<int, 0>{});
    phase(t + 1, 0, std::integral_constant<int, BUFSZ>{});
    phase(t + 1, 1, std::integral_constant<int, BUFSZ>{});
  }

#pragma unroll
  for (int m = 0; m < 8; m++) {
#pragma unroll
    for (int n = 0; n < NREP; n++) {
#pragma unroll
      for (int r = 0; r < 4; r++) {
        const int row = bm + wm * 128 + m * 16 + ((l >> 4) << 2) + r;
        const int col = bn + wn * (BN / 4) + n * 16 + (l & 15);
        const float v = acc[m][n][r];
        if (MODE == 1) {
          ((float*)o0)[(size_t)row * 2048 + col] = v;
        } else {
          const unsigned short q = f2bf(v);
          if (col < 2048) {
            ((unsigned short*)o0)[(size_t)row * 2048 + col] = q;
          } else if (col < 2560) {
            ((unsigned short*)o1)[(size_t)row * 512 + (col - 2048)] = q;
          } else {
            const int cv = col - 2560;
            ((unsigned short*)o2)[((size_t)(((row >> 11) * NKVc + (cv >> 7)) * HDc + (cv & 127)) << 11) +
                                  (row & 2047)] = q;
          }
        }
      }
    }
  }
}

// ---------------- K RoPE + relayout: raw[tok][kv*128+d] -> [b][kv][s][d] ----
__global__ __launch_bounds__(256) void rope_k(const unsigned short* __restrict__ raw,
                                              unsigned short* __restrict__ dst,
                                              const float* __restrict__ cosT,
                                              const float* __restrict__ sinT) {
  const int t = blockIdx.x * 256 + threadIdx.x;
  const int d = t & 63;
  const int h = (t >> 6) & 3;
  const int tok = t >> 8;
  const int b = tok >> 11, s = tok & 2047;
  const float c = cosT[(s << 6) + d];
  const float sn = sinT[(s << 6) + d];
  const size_t src = (size_t)tok * 512 + h * 128 + d;
  const float x0 = bf2f(raw[src]);
  const float x1 = bf2f(raw[src + 64]);
  const size_t db = ((size_t)(b * NKVc + h) * Sc + s) * HDc + d;
  dst[db] = f2bf(x0 * c - x1 * sn);
  dst[db + 64] = f2bf(x1 * c + x0 * sn);
}

// ---------------- causal GQA flash attention (R12: de-paired, grid 512) -----
// grid 512 = 8 kvb x 64 u; t = u<32 ? 63-u : u-32 -> bids b and b+256 have
// NIT(t) summing to exactly 33 and co-reside on one CU under ordered
// dispatch -> 2 blocks/CU = 8 waves/CU. Block: 4 waves = 4 GQA heads,
// one 32-row q-tile, NIT = (t>>1)+1 KV-64 iterations, dbuf 2x32KB.
__global__ __launch_bounds__(256, 2) void attn_kernel(const unsigned short* __restrict__ Qraw,
                                                      const unsigned short* __restrict__ Kr,
                                                      const unsigned short* __restrict__ Vt,
                                                      unsigned short* __restrict__ O,
                                                      const float* __restrict__ cosT,
                                                      const float* __restrict__ sinT) {
  __shared__ __align__(16) char smem[65536];

  const int tid = threadIdx.x, w = tid >> 6, l = tid & 63;
  const int lq = l & 31, lh = l >> 5;
  const int kvb = blockIdx.x & 7;
  const int u = blockIdx.x >> 3;                 // 0..63
  const int t = (u < 32) ? (63 - u) : (u - 32);
  const int b = kvb >> 2, kvh = kvb & 3, h = kvh * 4 + w;
  const int NIT = (t >> 1) + 1;

  const char* Kb = (const char*)(Kr + (size_t)(b * NKVc + kvh) * Sc * HDc);
  const char* Vb = (const char*)(Vt + (size_t)(b * NKVc + kvh) * HDc * Sc);

  const int krow0 = tid >> 4;
  const int kcb = ((tid & 15) * 16) ^ ((krow0 & 7) << 4);
  const int vrow0 = tid >> 3;
  const int vcb = ((tid & 7) * 16) ^ ((vrow0 & 7) << 4);
  char* ldst = smem + tid * 16;

  auto stage = [&](int slot, int kt_) {
#pragma unroll
    for (int c = 0; c < 4; c++)
      gload_lds16(Kb + (size_t)(kt_ * 64 + krow0 + 16 * c) * 256 + kcb,
                  ldst + slot + c * 4096);
#pragma unroll
    for (int c = 0; c < 4; c++)
      gload_lds16(Vb + (size_t)(vrow0 + 32 * c) * 4096 + kt_ * 128 + vcb,
                  ldst + slot + 16384 + c * 4096);
  };

  const int swz = (l & 7) << 4;
  const int hi16 = lh << 4;
  int co[8];
#pragma unroll
  for (int kc = 0; kc < 8; kc++) co[kc] = (kc * 32 + hi16) ^ swz;
  const int kbase = lq * 256;
  const int vbase = 16384 + lq * 128;

  bf16x8 qf[8];
  {
    const int srow = t * 32 + lq;
    const unsigned short* Qp = Qraw + ((size_t)(b * Sc + srow) << 11) + h * 128 + lh * 8;
#pragma unroll
    for (int kc = 0; kc < 4; kc++) {
      const bf16x8 vlo = *(const bf16x8*)(Qp + kc * 16);
      const bf16x8 vhi = *(const bf16x8*)(Qp + kc * 16 + 64);
      const float* cp = cosT + ((size_t)srow << 6) + kc * 16 + lh * 8;
      const float* sp = sinT + ((size_t)srow << 6) + kc * 16 + lh * 8;
      const float4 c0 = *(const float4*)cp, c1 = *(const float4*)(cp + 4);
      const float4 s0v = *(const float4*)sp, s1v = *(const float4*)(sp + 4);
      const float cs[8] = {c0.x, c0.y, c0.z, c0.w, c1.x, c1.y, c1.z, c1.w};
      const float ss[8] = {s0v.x, s0v.y, s0v.z, s0v.w, s1v.x, s1v.y, s1v.z, s1v.w};
#pragma unroll
      for (int j = 0; j < 8; j++) {
        const float xl = (float)vlo[j] * QSCALE;
        const float xh = (float)vhi[j] * QSCALE;
        qf[kc][j] = (__bf16)(xl * cs[j] - xh * ss[j]);
        qf[kc + 4][j] = (__bf16)(xh * cs[j] + xl * ss[j]);
      }
    }
  }

  f32x16 oacc[4];
#pragma unroll
  for (int d = 0; d < 4; d++)
#pragma unroll
    for (int r = 0; r < 16; r++) oacc[d][r] = 0.f;
  float m_run = -1e30f, sum_run = 0.f;

  stage(0, 0);

  auto iter = [&](int i, auto slotc) {
    constexpr int SLOT = decltype(slotc)::value;
    if (i + 1 < NIT) {
      stage(SLOT ^ 32768, i + 1);
      asm volatile("s_waitcnt vmcnt(8)" ::: "memory");
    } else {
      asm volatile("s_waitcnt vmcnt(0)" ::: "memory");
    }
    __builtin_amdgcn_s_barrier();

    f32x16 s0, s1;
#pragma unroll
    for (int r = 0; r < 16; r++) { s0[r] = 0.f; s1[r] = 0.f; }
    __builtin_amdgcn_s_setprio(1);
#pragma unroll
    for (int kc = 0; kc < 8; kc++) {
      const bf16x8 kf0 = *(const bf16x8*)(smem + SLOT + kbase + co[kc]);
      const bf16x8 kf1 = *(const bf16x8*)(smem + SLOT + 8192 + kbase + co[kc]);
      s0 = mfma32(kf0, qf[kc], s0);
      s1 = mfma32(kf1, qf[kc], s1);
    }
    __builtin_amdgcn_s_setprio(0);

    if (i == NIT - 1) {                    // diagonal: causal mask
      const int qpos = t * 32 + lq;
      const int kv0 = i * 64 + 4 * lh;
#pragma unroll
      for (int r = 0; r < 16; r++) {
        const int kvv = kv0 + (r & 3) + 8 * (r >> 2);
        if (kvv > qpos) s0[r] = -1e30f;
        if (kvv + 32 > qpos) s1[r] = -1e30f;
      }
    }

    float q8[8];
#pragma unroll
    for (int g4 = 0; g4 < 4; g4++) {
      q8[g4] = fmaxf(fmaxf(s0[4 * g4], s0[4 * g4 + 1]), fmaxf(s0[4 * g4 + 2], s0[4 * g4 + 3]));
      q8[4 + g4] = fmaxf(fmaxf(s1[4 * g4], s1[4 * g4 + 1]), fmaxf(s1[4 * g4 + 2], s1[4 * g4 + 3]));
    }
    float mt = fmaxf(fmaxf(fmaxf(q8[0], q8[1]), fmaxf(q8[2], q8[3])),
                     fmaxf(fmaxf(q8[4], q8[5]), fmaxf(q8[6], q8[7])));
    mt = fmaxf(mt, __shfl_xor(mt, 32));
    if (!__all(mt <= m_run + DEFER_THR)) {
      const float mn = fmaxf(m_run, mt);
      const float al = exp2f(m_run - mn);
      m_run = mn;
      sum_run *= al;
#pragma unroll
      for (int d = 0; d < 4; d++)
#pragma unroll
        for (int r = 0; r < 16; r++) oacc[d][r] *= al;
    }

    float pv0[16], pv1[16];
    float sA = 0.f, sB = 0.f, sC = 0.f, sD = 0.f;
#pragma unroll
    for (int r = 0; r < 16; r += 4) {
      pv0[r] = exp2f(s0[r] - m_run);         sA += pv0[r];
      pv0[r + 1] = exp2f(s0[r + 1] - m_run); sB += pv0[r + 1];
      pv0[r + 2] = exp2f(s0[r + 2] - m_run); sC += pv0[r + 2];
      pv0[r + 3] = exp2f(s0[r + 3] - m_run); sD += pv0[r + 3];
    }
#pragma unroll
    for (int r = 0; r < 16; r += 4) {
      pv1[r] = exp2f(s1[r] - m_run);         sA += pv1[r];
      pv1[r + 1] = exp2f(s1[r + 1] - m_run); sB += pv1[r + 1];
      pv1[r + 2] = exp2f(s1[r + 2] - m_run); sC += pv1[r + 2];
      pv1[r + 3] = exp2f(s1[r + 3] - m_run); sD += pv1[r + 3];
    }
    sum_run += (sA + sB) + (sC + sD);

    bf16x8 pf0, pf1, pf2, pf3;
    {
      unsigned a0 = cvtpk(pv0[0], pv0[1]), a2 = cvtpk(pv0[4], pv0[5]);
      unsigned a1 = cvtpk(pv0[2], pv0[3]), a3 = cvtpk(pv0[6], pv0[7]);
      pswap(a0, a2); pswap(a1, a3);
      i32x4 t4 = {(int)a0, (int)a1, (int)a2, (int)a3};
      pf0 = __builtin_bit_cast(bf16x8, t4);
    }
    {
      unsigned a0 = cvtpk(pv0[8], pv0[9]), a2 = cvtpk(pv0[12], pv0[13]);
      unsigned a1 = cvtpk(pv0[10], pv0[11]), a3 = cvtpk(pv0[14], pv0[15]);
      pswap(a0, a2); pswap(a1, a3);
      i32x4 t4 = {(int)a0, (int)a1, (int)a2, (int)a3};
      pf1 = __builtin_bit_cast(bf16x8, t4);
    }
    {
      unsigned a0 = cvtpk(pv1[0], pv1[1]), a2 = cvtpk(pv1[4], pv1[5]);
      unsigned a1 = cvtpk(pv1[2], pv1[3]), a3 = cvtpk(pv1[6], pv1[7]);
      pswap(a0, a2); pswap(a1, a3);
      i32x4 t4 = {(int)a0, (int)a1, (int)a2, (int)a3};
      pf2 = __builtin_bit_cast(bf16x8, t4);
    }
    {
      unsigned a0 = cvtpk(pv1[8], pv1[9]), a2 = cvtpk(pv1[12], pv1[13]);
      unsigned a1 = cvtpk(pv1[10], pv1[11]), a3 = cvtpk(pv1[14], pv1[15]);
      pswap(a0, a2); pswap(a1, a3);
      i32x4 t4 = {(int)a0, (int)a1, (int)a2, (int)a3};
      pf3 = __builtin_bit_cast(bf16x8, t4);
    }

    __builtin_amdgcn_s_setprio(1);
#pragma unroll
    for (int d = 0; d < 4; d++) {
      oacc[d] = mfma32(*(const bf16x8*)(smem + SLOT + vbase + d * 4096 + co[0]), pf0, oacc[d]);
      oacc[d] = mfma32(*(const bf16x8*)(smem + SLOT + vbase + d * 4096 + co[1]), pf1, oacc[d]);
      oacc[d] = mfma32(*(const bf16x8*)(smem + SLOT + vbase + d * 4096 + co[2]), pf2, oacc[d]);
      oacc[d] = mfma32(*(const bf16x8*)(smem + SLOT + vbase + d * 4096 + co[3]), pf3, oacc[d]);
    }
    __builtin_amdgcn_s_setprio(0);

    asm volatile("s_waitcnt lgkmcnt(0)" ::: "memory");
  };

  for (int i = 0; i < NIT; i += 2) {
    iter(i, std::integral_constant<int, 0>{});
    if (i + 1 < NIT) iter(i + 1, std::integral_constant<int, 32768>{});
  }

  // epilogue: normalize, write O^T (lane q = col, d in regs)
  const float st = sum_run + __shfl_xor(sum_run, 32);
  const float rinv = 1.0f / st;
  unsigned short* Op = O + ((size_t)(b * Sc + t * 32 + lq) << 11) + h * 128 + lh * 4;
#pragma unroll
  for (int d = 0; d < 4; d++) {
#pragma unroll
    for (int rq = 0; rq < 4; rq++) {
      uint2 u2;
      u2.x = cvtpk(oacc[d][4 * rq] * rinv, oacc[d][4 * rq + 1] * rinv);
      u2.y = cvtpk(oacc[d][4 * rq + 2] * rinv, oacc[d][4 * rq + 3] * rinv);
      *(uint2*)(Op + d * 32 + rq * 8) = u2;
    }
  }
}

// ---------------------------------------------------------------------------
extern "C" void kernel_launch(void* const* d_in, const int* in_sizes, int n_in,
                              void* d_out, int out_size, void* d_ws, size_t ws_size,
                              hipStream_t stream) {
  (void)in_sizes; (void)n_in; (void)out_size; (void)ws_size;
  const float* X = (const float*)d_in[0];
  const float* Wq = (const float*)d_in[1];
  const float* Wk = (const float*)d_in[2];
  const float* Wv = (const float*)d_in[3];
  const float* Wo = (const float*)d_in[4];

  char* ws = (char*)d_ws;
  unsigned short* Xbf  = (unsigned short*)(ws + 0);         // 4096x2048 (16MB)
  unsigned short* Wqkv = (unsigned short*)(ws + 16777216);  // 3072x2048 (12.6MB)
  unsigned short* Wob  = (unsigned short*)(ws + 29360128);  // 2048x2048 (8MB)
  unsigned short* Qraw = (unsigned short*)(ws + 37748736);  // 4096x2048 (16MB)
  unsigned short* Kraw = (unsigned short*)(ws + 54525952);  // 4096x512  (4MB)
  unsigned short* Vt   = (unsigned short*)(ws + 58720256);  // [b][kv][d][s] (4MB)
  float*          cosT = (float*)(ws + 62914560);           // 2048x64 f32 (512KB)
  float*          sinT = (float*)(ws + 63438848);           // 2048x64 f32 (512KB)
  unsigned short* Kr   = (unsigned short*)(ws + 79691776);  // [b][kv][s][d] (4MB)
  unsigned short* Ows  = (unsigned short*)(ws + 83886080);  // 4096x2048 (16MB)

  rope_table<<<512, 256, 0, stream>>>(cosT, sinT);
  cvt_kernel<<<8192, 256, 0, stream>>>(X, Xbf, 2097152);
  cvt_weights<<<10240, 256, 0, stream>>>(Wq, Wk, Wv, Wo, Wqkv, Wob);

  gemm2p<192, 2><<<256, 512, 0, stream>>>(Xbf, Wqkv, Qraw, Kraw, Vt);

  rope_k<<<4096, 256, 0, stream>>>(Kraw, Kr, cosT, sinT);

  attn_kernel<<<512, 256, 0, stream>>>(Qraw, Kr, Vt, Ows, cosT, sinT);

  gemm2p<128, 1><<<256, 512, 0, stream>>>(Ows, Wob, d_out, nullptr, nullptr);
}